// Round 2
// baseline (931.723 us; speedup 1.0000x reference)
//
#include <hip/hip_runtime.h>
#include <math.h>

#define N_IMG 16
#define N_CLS 80
#define K_PRE 1000
#define K_POST 100
#define CAND 3000
#define NPAIR 48
#define NBIN 8192
#define BSHIFT 19          // 13-bit bin = key >> 19
#define CAP 4096           // per-pair candidate superset capacity
#define IDXM 0xFFFFFu      // 20-bit packed (loc*80+c) index
#define NCG 5              // class groups per (img,lvl)
#define CPB 16             // classes per block

// ---- workspace layout (bytes) ----
#define HIST_OFF   0                 // uint[48*8192]  = 1572864
#define CNT_OFF    1572864           // uint[48]
#define TBIN_OFF   1573056           // uint[48]
#define ZERO_BYTES 1573248
#define LIST_OFF   1573248           // u64[48*4096]   = 1572864 -> 3146112
#define CANDF_OFF  3146112           // uint[48000]    -> 3338112
#define CANDS_OFF  3338112           // float[48000]   -> 3530112
#define DBOX_OFF   3530112           // float4[48000]  -> 4298112 (16B aligned)
#define DSC_OFF    4298112           // float[48000]   -> 4490112
#define DCLS_OFF   4490112           // int[48000]     -> 4682112

__device__ __forceinline__ float sigm(float x) { return 1.0f / (1.0f + expf(-x)); }
__device__ __forceinline__ int lvl_hw(int lvl) { return lvl == 0 ? 10000 : (lvl == 1 ? 2500 : 625); }

// ---------------- scan 1: 13-bit histogram ----------------
__global__ __launch_bounds__(256) void hist_k(
        const float* __restrict__ cls0, const float* __restrict__ cls1, const float* __restrict__ cls2,
        const float* __restrict__ ctr0, const float* __restrict__ ctr1, const float* __restrict__ ctr2,
        unsigned* __restrict__ hist) {
    __shared__ unsigned lh[NBIN];
    const int lvl = blockIdx.z, img = blockIdx.y;
    const int cg = blockIdx.x % NCG, locb = blockIdx.x / NCG;
    const float* cls = lvl == 0 ? cls0 : (lvl == 1 ? cls1 : cls2);
    const float* ctr = lvl == 0 ? ctr0 : (lvl == 1 ? ctr1 : ctr2);
    const int HW = lvl_hw(lvl);
    const int p = img * 3 + lvl;
    for (int i = threadIdx.x; i < NBIN; i += 256) lh[i] = 0;
    __syncthreads();
    const int base = (locb * 256 + threadIdx.x) * 4;
    if (base < HW) {
        const float* clsI = cls + (size_t)img * N_CLS * HW + (size_t)cg * CPB * HW;
        const float* ctrI = ctr + (size_t)img * HW;
        if (base + 3 < HW && (HW & 3) == 0) {
            float4 cv = *(const float4*)(ctrI + base);
            float s0 = sigm(cv.x), s1 = sigm(cv.y), s2 = sigm(cv.z), s3 = sigm(cv.w);
            for (int c = 0; c < CPB; ++c) {
                float4 v = *(const float4*)(clsI + (size_t)c * HW + base);
                float cp;
                cp = sigm(v.x); if (cp > 0.05f) atomicAdd(&lh[__float_as_uint(cp * s0) >> BSHIFT], 1u);
                cp = sigm(v.y); if (cp > 0.05f) atomicAdd(&lh[__float_as_uint(cp * s1) >> BSHIFT], 1u);
                cp = sigm(v.z); if (cp > 0.05f) atomicAdd(&lh[__float_as_uint(cp * s2) >> BSHIFT], 1u);
                cp = sigm(v.w); if (cp > 0.05f) atomicAdd(&lh[__float_as_uint(cp * s3) >> BSHIFT], 1u);
            }
        } else {
            for (int k = 0; k < 4; ++k) {
                if (base + k >= HW) break;
                float cs = sigm(ctrI[base + k]);
                for (int c = 0; c < CPB; ++c) {
                    float cp = sigm(clsI[(size_t)c * HW + base + k]);
                    if (cp > 0.05f) atomicAdd(&lh[__float_as_uint(cp * cs) >> BSHIFT], 1u);
                }
            }
        }
    }
    __syncthreads();
    unsigned* h = hist + (size_t)p * NBIN;
    for (int i = threadIdx.x; i < NBIN; i += 256) { unsigned v = lh[i]; if (v) atomicAdd(&h[i], v); }
}

// ---------------- threshold bin per pair ----------------
__global__ __launch_bounds__(256) void scan_k(const unsigned* __restrict__ hist, unsigned* __restrict__ tbin) {
    __shared__ unsigned csum[256];
    __shared__ unsigned suf[256];
    const int p = blockIdx.x, t = threadIdx.x;
    const unsigned* h = hist + (size_t)p * NBIN;
    unsigned ms = 0;
    for (int j = 0; j < 32; ++j) ms += h[t * 32 + j];
    csum[t] = ms;
    __syncthreads();
    if (t == 0) {
        unsigned a = 0;
        for (int i = 255; i >= 0; --i) { suf[i] = a; a += csum[i]; }
    }
    __syncthreads();
    unsigned A = suf[t];
    for (int j = 31; j >= 0; --j) {
        unsigned c = h[t * 32 + j];
        if (A < K_PRE && A + c >= K_PRE) tbin[p] = (unsigned)(t * 32 + j);
        A += c;
    }
}

// ---------------- scan 2: compact superset ----------------
__device__ __forceinline__ void try_emit(float cp, float cs, unsigned idx, unsigned Tb,
                                         unsigned* cntp, unsigned long long* listp) {
    if (cp > 0.05f) {
        unsigned key = __float_as_uint(cp * cs);
        if ((key >> BSHIFT) >= Tb) {
            unsigned slot = atomicAdd(cntp, 1u);
            if (slot < CAP)
                listp[slot] = ((unsigned long long)key << 20) | (unsigned long long)(IDXM ^ idx);
        }
    }
}

__global__ __launch_bounds__(256) void compact_k(
        const float* __restrict__ cls0, const float* __restrict__ cls1, const float* __restrict__ cls2,
        const float* __restrict__ ctr0, const float* __restrict__ ctr1, const float* __restrict__ ctr2,
        const unsigned* __restrict__ tbin, unsigned* __restrict__ cnt, unsigned long long* __restrict__ list) {
    const int lvl = blockIdx.z, img = blockIdx.y;
    const int cg = blockIdx.x % NCG, locb = blockIdx.x / NCG;
    const float* cls = lvl == 0 ? cls0 : (lvl == 1 ? cls1 : cls2);
    const float* ctr = lvl == 0 ? ctr0 : (lvl == 1 ? ctr1 : ctr2);
    const int HW = lvl_hw(lvl);
    const int p = img * 3 + lvl;
    const unsigned Tb = tbin[p];
    unsigned* cntp = cnt + p;
    unsigned long long* listp = list + (size_t)p * CAP;
    const int base = (locb * 256 + threadIdx.x) * 4;
    if (base >= HW) return;
    const float* clsI = cls + (size_t)img * N_CLS * HW + (size_t)cg * CPB * HW;
    const float* ctrI = ctr + (size_t)img * HW;
    const int c0 = cg * CPB;
    if (base + 3 < HW && (HW & 3) == 0) {
        float4 cv = *(const float4*)(ctrI + base);
        float s0 = sigm(cv.x), s1 = sigm(cv.y), s2 = sigm(cv.z), s3 = sigm(cv.w);
        for (int c = 0; c < CPB; ++c) {
            float4 v = *(const float4*)(clsI + (size_t)c * HW + base);
            unsigned ib = (unsigned)(base * N_CLS + c0 + c);
            try_emit(sigm(v.x), s0, ib,               Tb, cntp, listp);
            try_emit(sigm(v.y), s1, ib + N_CLS,       Tb, cntp, listp);
            try_emit(sigm(v.z), s2, ib + 2 * N_CLS,   Tb, cntp, listp);
            try_emit(sigm(v.w), s3, ib + 3 * N_CLS,   Tb, cntp, listp);
        }
    } else {
        for (int k = 0; k < 4; ++k) {
            if (base + k >= HW) break;
            float cs = sigm(ctrI[base + k]);
            for (int c = 0; c < CPB; ++c) {
                float cp = sigm(clsI[(size_t)c * HW + base + k]);
                try_emit(cp, cs, (unsigned)((base + k) * N_CLS + c0 + c), Tb, cntp, listp);
            }
        }
    }
}

// ---------------- exact top-1000 per pair (bitonic on u64) ----------------
__global__ __launch_bounds__(256) void select_k(const unsigned* __restrict__ cnt,
                                                const unsigned long long* __restrict__ list,
                                                unsigned* __restrict__ candF, float* __restrict__ candS) {
    __shared__ unsigned long long sk[CAP];   // 32 KB
    const int p = blockIdx.x, t = threadIdx.x;
    int n = (int)cnt[p]; if (n > CAP) n = CAP;
    const unsigned long long* lp = list + (size_t)p * CAP;
    for (int i = t; i < CAP; i += 256) sk[i] = (i < n) ? lp[i] : 0ull;
    __syncthreads();
    for (int k = 2; k <= CAP; k <<= 1)
        for (int j = k >> 1; j > 0; j >>= 1) {
            for (int i = t; i < CAP; i += 256) {
                int ixj = i ^ j;
                if (ixj > i) {
                    unsigned long long a = sk[i], b = sk[ixj];
                    bool up = ((i & k) == 0);
                    if (up ? (a < b) : (a > b)) { sk[i] = b; sk[ixj] = a; }  // descending
                }
            }
            __syncthreads();
        }
    for (int i = t; i < K_PRE; i += 256) {
        unsigned long long u = sk[i];
        int o = p * K_PRE + i;
        if (u != 0ull) {
            candS[o] = __uint_as_float((unsigned)(u >> 20));
            candF[o] = IDXM ^ (unsigned)(u & IDXM);
        } else { candS[o] = -1.0f; candF[o] = 0u; }
    }
}

// ---------------- box decode ----------------
__global__ __launch_bounds__(256) void decode_k(
        const float* __restrict__ loc0, const float* __restrict__ loc1, const float* __restrict__ loc2,
        const float* __restrict__ reg0, const float* __restrict__ reg1, const float* __restrict__ reg2,
        const unsigned* __restrict__ candF, const float* __restrict__ candS,
        float4* __restrict__ dbox, float* __restrict__ dsc, int* __restrict__ dcls) {
    int i = blockIdx.x * blockDim.x + threadIdx.x;
    if (i >= NPAIR * K_PRE) return;
    int p = i / K_PRE, slot = i % K_PRE;
    int img = p / 3, lvl = p % 3;
    int out = img * CAND + lvl * K_PRE + slot;
    float s = candS[i];
    if (!(s > 0.0f)) {
        dbox[out] = make_float4(0.f, 0.f, 0.f, 0.f);
        dsc[out] = -1.0f;
        dcls[out] = 0;
        return;
    }
    const float* locs = lvl == 0 ? loc0 : (lvl == 1 ? loc1 : loc2);
    const float* reg  = lvl == 0 ? reg0 : (lvl == 1 ? reg1 : reg2);
    const int HW = lvl_hw(lvl);
    const float stridef = lvl == 0 ? 8.0f : (lvl == 1 ? 16.0f : 32.0f);
    unsigned e = candF[i];
    int loc = (int)(e / N_CLS);
    int c = (int)(e % N_CLS) + 1;
    const float* r = reg + (size_t)img * 4 * HW;
    float l = r[0 * HW + loc] * stridef;
    float t = r[1 * HW + loc] * stridef;
    float rr = r[2 * HW + loc] * stridef;
    float b = r[3 * HW + loc] * stridef;
    float x = locs[loc * 2], y = locs[loc * 2 + 1];
    float x1 = fminf(fmaxf(x - l, 0.f), 800.f);
    float y1 = fminf(fmaxf(y - t, 0.f), 800.f);
    float x2 = fminf(fmaxf(x + rr, 0.f), 800.f);
    float y2 = fminf(fmaxf(y + b, 0.f), 800.f);
    dbox[out] = make_float4(x1, y1, x2, y2);
    dsc[out] = sqrtf(s);
    dcls[out] = c;
}

// ---------------- sort + wave-serial greedy NMS ----------------
__global__ __launch_bounds__(256) void nms_k(const float4* __restrict__ dbox, const float* __restrict__ dsc,
                                             const int* __restrict__ dcls, float* __restrict__ out) {
    __shared__ unsigned long long sk[4096];   // 32 KB
    __shared__ float4 wbox[512];
    __shared__ float  warea[512];
    __shared__ float  wscore[512];
    __shared__ int    wcls[512];
    __shared__ int    walive[512];
    __shared__ float4 kbox[K_POST];
    __shared__ float  karea[K_POST];
    __shared__ float  kscore[K_POST];
    __shared__ int    kcls[K_POST];
    __shared__ int    s_keptn, s_done;
    const int img = blockIdx.x, tid = threadIdx.x;
    if (tid == 0) { s_keptn = 0; s_done = 0; }
    for (int i = tid; i < 4096; i += 256) {
        unsigned long long u = 0ull;
        if (i < CAND) {
            float s = dsc[img * CAND + i];
            if (s > 0.0f)
                u = ((unsigned long long)__float_as_uint(s) << 12) | (unsigned long long)(4095 - i);
        }
        sk[i] = u;
    }
    __syncthreads();
    for (int k = 2; k <= 4096; k <<= 1)
        for (int j = k >> 1; j > 0; j >>= 1) {
            for (int i = tid; i < 4096; i += 256) {
                int ixj = i ^ j;
                if (ixj > i) {
                    unsigned long long a = sk[i], b = sk[ixj];
                    bool up = ((i & k) == 0);
                    if (up ? (a < b) : (a > b)) { sk[i] = b; sk[ixj] = a; }  // descending
                }
            }
            __syncthreads();
        }
    const int lane = tid & 63;
    for (int winbase = 0; winbase < CAND; winbase += 512) {
        __syncthreads();
        if (s_done) break;
        const int kn0 = s_keptn;
        // parallel window load + filter vs already-kept boxes
        for (int q = tid; q < 512; q += 256) {
            int alive = 0; float4 b = make_float4(0.f, 0.f, 0.f, 0.f);
            float ar = 0.f, sc = 0.f; int cl = 0;
            int pos = winbase + q;
            if (pos < CAND) {
                unsigned long long u = sk[pos];
                if (u != 0ull) {
                    int cand = 4095 - (int)(u & 0xFFFull);
                    sc = __uint_as_float((unsigned)(u >> 12));
                    b = dbox[img * CAND + cand];
                    cl = dcls[img * CAND + cand];
                    ar = (b.z - b.x) * (b.w - b.y);
                    alive = 1;
                    for (int k2 = 0; k2 < kn0; ++k2) {
                        if (kcls[k2] == cl) {
                            float4 kb = kbox[k2];
                            float xx1 = fmaxf(kb.x, b.x), yy1 = fmaxf(kb.y, b.y);
                            float xx2 = fminf(kb.z, b.z), yy2 = fminf(kb.w, b.w);
                            float inter = fmaxf(xx2 - xx1, 0.f) * fmaxf(yy2 - yy1, 0.f);
                            float iou = inter / (ar + karea[k2] - inter + 1e-9f);
                            if (iou > 0.6f) { alive = 0; break; }
                        }
                    }
                }
            }
            wbox[q] = b; warea[q] = ar; wscore[q] = sc; wcls[q] = cl; walive[q] = alive;
        }
        __syncthreads();
        // wave 0: serial greedy resolve inside the window (wave-synchronous, no barriers)
        if (tid < 64) {
            int kn = kn0;
            while (kn < K_POST) {
                int e = -1;
                for (int slot = 0; slot < 8; ++slot) {
                    unsigned long long m = __ballot(walive[slot * 64 + lane] != 0);
                    if (m) { e = slot * 64 + (int)(__ffsll((unsigned long long)m) - 1); break; }
                }
                if (e < 0) break;
                float4 pb = wbox[e]; float pa = warea[e]; float ps = wscore[e]; int pc = wcls[e];
                if (lane == 0) { kbox[kn] = pb; karea[kn] = pa; kscore[kn] = ps; kcls[kn] = pc; }
                kn++;
                for (int slot = 0; slot < 8; ++slot) {
                    int e2 = slot * 64 + lane;
                    if (walive[e2]) {
                        bool kill = (e2 == e);
                        if (!kill && wcls[e2] == pc) {
                            float4 b2 = wbox[e2];
                            float xx1 = fmaxf(pb.x, b2.x), yy1 = fmaxf(pb.y, b2.y);
                            float xx2 = fminf(pb.z, b2.z), yy2 = fminf(pb.w, b2.w);
                            float inter = fmaxf(xx2 - xx1, 0.f) * fmaxf(yy2 - yy1, 0.f);
                            float iou = inter / (warea[e2] + pa - inter + 1e-9f);
                            if (iou > 0.6f) kill = true;
                        }
                        if (kill) walive[e2] = 0;
                    }
                }
            }
            if (lane == 0) { s_keptn = kn; if (kn >= K_POST) s_done = 1; }
        }
    }
    __syncthreads();
    const int kn = s_keptn;
    for (int i = tid; i < K_POST; i += 256) {
        float4 b = make_float4(0.f, 0.f, 0.f, 0.f);
        float sc = 0.f, cl = 0.f, kp = 0.f;
        if (i < kn) { b = kbox[i]; sc = kscore[i]; cl = (float)kcls[i]; kp = 1.0f; }
        float* bo = out + (size_t)(img * K_POST + i) * 4;
        bo[0] = b.x; bo[1] = b.y; bo[2] = b.z; bo[3] = b.w;
        out[N_IMG * K_POST * 4 + img * K_POST + i] = sc;
        out[N_IMG * K_POST * 5 + img * K_POST + i] = cl;
        out[N_IMG * K_POST * 6 + img * K_POST + i] = kp;
    }
}

extern "C" void kernel_launch(void* const* d_in, const int* in_sizes, int n_in,
                              void* d_out, int out_size, void* d_ws, size_t ws_size,
                              hipStream_t stream) {
    const float* loc0 = (const float*)d_in[0];
    const float* cls0 = (const float*)d_in[1];
    const float* reg0 = (const float*)d_in[2];
    const float* ctr0 = (const float*)d_in[3];
    const float* loc1 = (const float*)d_in[4];
    const float* cls1 = (const float*)d_in[5];
    const float* reg1 = (const float*)d_in[6];
    const float* ctr1 = (const float*)d_in[7];
    const float* loc2 = (const float*)d_in[8];
    const float* cls2 = (const float*)d_in[9];
    const float* reg2 = (const float*)d_in[10];
    const float* ctr2 = (const float*)d_in[11];

    char* ws = (char*)d_ws;
    unsigned*            hist  = (unsigned*)(ws + HIST_OFF);
    unsigned*            cnt   = (unsigned*)(ws + CNT_OFF);
    unsigned*            tbin  = (unsigned*)(ws + TBIN_OFF);
    unsigned long long*  list  = (unsigned long long*)(ws + LIST_OFF);
    unsigned*            candF = (unsigned*)(ws + CANDF_OFF);
    float*               candS = (float*)(ws + CANDS_OFF);
    float4*              dbox  = (float4*)(ws + DBOX_OFF);
    float*               dsc   = (float*)(ws + DSC_OFF);
    int*                 dcls  = (int*)(ws + DCLS_OFF);
    float*               out   = (float*)d_out;

    hipMemsetAsync(ws, 0, ZERO_BYTES, stream);

    const dim3 sg(10 * NCG, N_IMG, 3);
    hist_k<<<sg, 256, 0, stream>>>(cls0, cls1, cls2, ctr0, ctr1, ctr2, hist);
    scan_k<<<NPAIR, 256, 0, stream>>>(hist, tbin);
    compact_k<<<sg, 256, 0, stream>>>(cls0, cls1, cls2, ctr0, ctr1, ctr2, tbin, cnt, list);
    select_k<<<NPAIR, 256, 0, stream>>>(cnt, list, candF, candS);
    decode_k<<<(NPAIR * K_PRE + 255) / 256, 256, 0, stream>>>(
        loc0, loc1, loc2, reg0, reg1, reg2, candF, candS, dbox, dsc, dcls);
    nms_k<<<N_IMG, 256, 0, stream>>>(dbox, dsc, dcls, out);
}

// Round 3
// 611.389 us; speedup vs baseline: 1.5239x; 1.5239x over previous
//
#include <hip/hip_runtime.h>
#include <math.h>

#define N_IMG 16
#define N_CLS 80
#define K_PRE 1000
#define K_POST 100
#define NPAIR 48
#define NBIN 8192
#define BSHIFT 19          // 13-bit bin = key >> 19
#define CAP 4096           // per-pair candidate superset capacity
#define IDXM 0xFFFFFu      // 20-bit packed (loc*80+c) index
#define NCG 5              // class groups per (img,lvl)
#define CPB 16             // classes per block
#define CHUNK 256

// ---- workspace layout (bytes) ----
#define HIST_OFF   0                 // uint[48*8192]  = 1572864
#define CNT_OFF    1572864           // uint[48]
#define TBIN_OFF   1573056           // uint[48]
#define ZERO_BYTES 1573248
#define LIST_OFF   1573248           // u64[48*4096]   -> 3146112
#define CANDF_OFF  3146112           // uint[48000]    -> 3338112
#define CANDS_OFF  3338112           // float[48000]   -> 3530112

__device__ __forceinline__ float sigm(float x) { return 1.0f / (1.0f + __expf(-x)); }
__device__ __forceinline__ int lvl_hw(int lvl) { return lvl == 0 ? 10000 : (lvl == 1 ? 2500 : 625); }

// ---------------- scan 1: 13-bit histogram ----------------
__global__ __launch_bounds__(256) void hist_k(
        const float* __restrict__ cls0, const float* __restrict__ cls1, const float* __restrict__ cls2,
        const float* __restrict__ ctr0, const float* __restrict__ ctr1, const float* __restrict__ ctr2,
        unsigned* __restrict__ hist) {
    __shared__ unsigned lh[NBIN];
    const int lvl = blockIdx.z, img = blockIdx.y;
    const int cg = blockIdx.x % NCG, locb = blockIdx.x / NCG;
    const float* cls = lvl == 0 ? cls0 : (lvl == 1 ? cls1 : cls2);
    const float* ctr = lvl == 0 ? ctr0 : (lvl == 1 ? ctr1 : ctr2);
    const int HW = lvl_hw(lvl);
    const int p = img * 3 + lvl;
    for (int i = threadIdx.x; i < NBIN; i += 256) lh[i] = 0;
    __syncthreads();
    const int base = (locb * 256 + threadIdx.x) * 4;
    if (base < HW) {
        const float* clsI = cls + (size_t)img * N_CLS * HW + (size_t)cg * CPB * HW;
        const float* ctrI = ctr + (size_t)img * HW;
        if (base + 3 < HW && (HW & 3) == 0) {
            float4 cv = *(const float4*)(ctrI + base);
            float s0 = sigm(cv.x), s1 = sigm(cv.y), s2 = sigm(cv.z), s3 = sigm(cv.w);
            for (int c = 0; c < CPB; ++c) {
                float4 v = *(const float4*)(clsI + (size_t)c * HW + base);
                float cp;
                cp = sigm(v.x); if (cp > 0.05f) atomicAdd(&lh[__float_as_uint(cp * s0) >> BSHIFT], 1u);
                cp = sigm(v.y); if (cp > 0.05f) atomicAdd(&lh[__float_as_uint(cp * s1) >> BSHIFT], 1u);
                cp = sigm(v.z); if (cp > 0.05f) atomicAdd(&lh[__float_as_uint(cp * s2) >> BSHIFT], 1u);
                cp = sigm(v.w); if (cp > 0.05f) atomicAdd(&lh[__float_as_uint(cp * s3) >> BSHIFT], 1u);
            }
        } else {
            for (int k = 0; k < 4; ++k) {
                if (base + k >= HW) break;
                float cs = sigm(ctrI[base + k]);
                for (int c = 0; c < CPB; ++c) {
                    float cp = sigm(clsI[(size_t)c * HW + base + k]);
                    if (cp > 0.05f) atomicAdd(&lh[__float_as_uint(cp * cs) >> BSHIFT], 1u);
                }
            }
        }
    }
    __syncthreads();
    unsigned* h = hist + (size_t)p * NBIN;
    for (int i = threadIdx.x; i < NBIN; i += 256) { unsigned v = lh[i]; if (v) atomicAdd(&h[i], v); }
}

// ---------------- threshold bin per pair ----------------
__global__ __launch_bounds__(256) void scan_k(const unsigned* __restrict__ hist, unsigned* __restrict__ tbin) {
    __shared__ unsigned csum[256];
    __shared__ unsigned suf[256];
    const int p = blockIdx.x, t = threadIdx.x;
    const unsigned* h = hist + (size_t)p * NBIN;
    unsigned ms = 0;
    for (int j = 0; j < 32; ++j) ms += h[t * 32 + j];
    csum[t] = ms;
    __syncthreads();
    if (t == 0) {
        unsigned a = 0;
        for (int i = 255; i >= 0; --i) { suf[i] = a; a += csum[i]; }
    }
    __syncthreads();
    unsigned A = suf[t];
    for (int j = 31; j >= 0; --j) {
        unsigned c = h[t * 32 + j];
        if (A < K_PRE && A + c >= K_PRE) tbin[p] = (unsigned)(t * 32 + j);
        A += c;
    }
}

// ---------------- scan 2: compact superset ----------------
__device__ __forceinline__ void try_emit(float cp, float cs, unsigned idx, unsigned Tb,
                                         unsigned* cntp, unsigned long long* listp) {
    if (cp > 0.05f) {
        unsigned key = __float_as_uint(cp * cs);
        if ((key >> BSHIFT) >= Tb) {
            unsigned slot = atomicAdd(cntp, 1u);
            if (slot < CAP)
                listp[slot] = ((unsigned long long)key << 20) | (unsigned long long)(IDXM ^ idx);
        }
    }
}

__global__ __launch_bounds__(256) void compact_k(
        const float* __restrict__ cls0, const float* __restrict__ cls1, const float* __restrict__ cls2,
        const float* __restrict__ ctr0, const float* __restrict__ ctr1, const float* __restrict__ ctr2,
        const unsigned* __restrict__ tbin, unsigned* __restrict__ cnt, unsigned long long* __restrict__ list) {
    const int lvl = blockIdx.z, img = blockIdx.y;
    const int cg = blockIdx.x % NCG, locb = blockIdx.x / NCG;
    const float* cls = lvl == 0 ? cls0 : (lvl == 1 ? cls1 : cls2);
    const float* ctr = lvl == 0 ? ctr0 : (lvl == 1 ? ctr1 : ctr2);
    const int HW = lvl_hw(lvl);
    const int p = img * 3 + lvl;
    const unsigned Tb = tbin[p];
    unsigned* cntp = cnt + p;
    unsigned long long* listp = list + (size_t)p * CAP;
    const int base = (locb * 256 + threadIdx.x) * 4;
    if (base >= HW) return;
    const float* clsI = cls + (size_t)img * N_CLS * HW + (size_t)cg * CPB * HW;
    const float* ctrI = ctr + (size_t)img * HW;
    const int c0 = cg * CPB;
    if (base + 3 < HW && (HW & 3) == 0) {
        float4 cv = *(const float4*)(ctrI + base);
        float s0 = sigm(cv.x), s1 = sigm(cv.y), s2 = sigm(cv.z), s3 = sigm(cv.w);
        for (int c = 0; c < CPB; ++c) {
            float4 v = *(const float4*)(clsI + (size_t)c * HW + base);
            unsigned ib = (unsigned)(base * N_CLS + c0 + c);
            try_emit(sigm(v.x), s0, ib,             Tb, cntp, listp);
            try_emit(sigm(v.y), s1, ib + N_CLS,     Tb, cntp, listp);
            try_emit(sigm(v.z), s2, ib + 2 * N_CLS, Tb, cntp, listp);
            try_emit(sigm(v.w), s3, ib + 3 * N_CLS, Tb, cntp, listp);
        }
    } else {
        for (int k = 0; k < 4; ++k) {
            if (base + k >= HW) break;
            float cs = sigm(ctrI[base + k]);
            for (int c = 0; c < CPB; ++c) {
                float cp = sigm(clsI[(size_t)c * HW + base + k]);
                try_emit(cp, cs, (unsigned)((base + k) * N_CLS + c0 + c), Tb, cntp, listp);
            }
        }
    }
}

// ---------------- exact top-1000 per pair (bitonic on u64, 512 thr) ----------------
__global__ __launch_bounds__(512) void select_k(const unsigned* __restrict__ cnt,
                                                const unsigned long long* __restrict__ list,
                                                unsigned* __restrict__ candF, float* __restrict__ candS) {
    __shared__ unsigned long long sk[CAP];   // 32 KB
    const int p = blockIdx.x, t = threadIdx.x;
    int n = (int)cnt[p]; if (n > CAP) n = CAP;
    const unsigned long long* lp = list + (size_t)p * CAP;
    for (int i = t; i < CAP; i += 512) sk[i] = (i < n) ? lp[i] : 0ull;
    __syncthreads();
    for (int k = 2; k <= CAP; k <<= 1)
        for (int j = k >> 1; j > 0; j >>= 1) {
            for (int i = t; i < CAP; i += 512) {
                int ixj = i ^ j;
                if (ixj > i) {
                    unsigned long long a = sk[i], b = sk[ixj];
                    bool up = ((i & k) == 0);
                    if (up ? (a < b) : (a > b)) { sk[i] = b; sk[ixj] = a; }  // descending
                }
            }
            __syncthreads();
        }
    for (int i = t; i < K_PRE; i += 512) {
        unsigned long long u = sk[i];
        int o = p * K_PRE + i;
        if (u != 0ull) {
            candS[o] = __uint_as_float((unsigned)(u >> 20));
            candF[o] = IDXM ^ (unsigned)(u & IDXM);
        } else { candS[o] = -1.0f; candF[o] = 0u; }
    }
}

// ---------------- merge 3 sorted lists + decode + bitmask greedy NMS ----------------
__global__ __launch_bounds__(256) void nms_k(
        const float* __restrict__ loc0, const float* __restrict__ loc1, const float* __restrict__ loc2,
        const float* __restrict__ reg0, const float* __restrict__ reg1, const float* __restrict__ reg2,
        const unsigned* __restrict__ candF, const float* __restrict__ candS,
        float* __restrict__ out) {
    __shared__ float skey[3000];
    __shared__ unsigned short sidx[3000];
    __shared__ float4 sbox[CHUNK], obox[CHUNK];
    __shared__ float sarea[CHUNK], sscor[CHUNK];
    __shared__ int scls[CHUNK];
    __shared__ unsigned adjW[CHUNK * 8];     // 8 KB, upper-triangle IoU>0.6 bits
    __shared__ unsigned aliveW[8];
    __shared__ float4 kbox[K_POST], kobox[K_POST];
    __shared__ float karea[K_POST], kscor[K_POST];
    __shared__ int kcls[K_POST];
    __shared__ int s_keptn, s_done;
    const int img = blockIdx.x, tid = threadIdx.x;
    if (tid == 0) { s_keptn = 0; s_done = 0; }
    for (int i = tid; i < 3000; i += 256) skey[i] = candS[img * 3000 + i];
    __syncthreads();
    // rank-merge: order = (score desc, lvl, slot) == reference concat + argmax tie rule
    for (int e = tid; e < 3000; e += 256) {
        int l = e >= 2000 ? 2 : (e >= 1000 ? 1 : 0);
        int slot = e - l * 1000;
        float s = skey[e];
        int rank = slot;
        for (int l2 = 0; l2 < 3; ++l2) {
            if (l2 == l) continue;
            const float* kb = skey + l2 * 1000;
            const bool eq = l2 < l;
            int lo = 0, hi = 1000;
            while (lo < hi) {
                int m = (lo + hi) >> 1;
                float v = kb[m];
                bool go = eq ? (v >= s) : (v > s);
                lo = go ? m + 1 : lo;
                hi = go ? hi : m;
            }
            rank += lo;
        }
        sidx[rank] = (unsigned short)e;
    }
    __syncthreads();
    for (int base = 0; base < 3000; base += CHUNK) {
        if (s_done) break;                   // uniform (read after barrier)
        const int kn0 = s_keptn;
        if (tid < 8) aliveW[tid] = 0u;
        __syncthreads();
        {   // decode + filter-vs-kept, one candidate per thread
            const int q = tid;
            const int r = base + q;
            float4 bx = make_float4(0.f, 0.f, 0.f, 0.f), ox = bx;
            float ar = 0.f, ssc = 0.f; int cl = 0, alive = 0;
            if (r < 3000) {
                int e = sidx[r];
                int l = e >= 2000 ? 2 : (e >= 1000 ? 1 : 0);
                int slot = e - l * 1000;
                float s = skey[e];
                if (s > 0.f) {
                    int p = img * 3 + l;
                    unsigned fi = candF[p * K_PRE + slot];
                    int loc = (int)(fi / (unsigned)N_CLS);
                    int c = (int)(fi % (unsigned)N_CLS) + 1;
                    const float* locs = l == 0 ? loc0 : (l == 1 ? loc1 : loc2);
                    const float* rg = l == 0 ? reg0 : (l == 1 ? reg1 : reg2);
                    const int HW = lvl_hw(l);
                    const float st = l == 0 ? 8.f : (l == 1 ? 16.f : 32.f);
                    const float* rb = rg + (size_t)img * 4 * HW;
                    float lv = rb[loc] * st, tv = rb[HW + loc] * st;
                    float rv = rb[2 * HW + loc] * st, bv = rb[3 * HW + loc] * st;
                    float x = locs[2 * loc], y = locs[2 * loc + 1];
                    float x1 = fminf(fmaxf(x - lv, 0.f), 800.f);
                    float y1 = fminf(fmaxf(y - tv, 0.f), 800.f);
                    float x2 = fminf(fmaxf(x + rv, 0.f), 800.f);
                    float y2 = fminf(fmaxf(y + bv, 0.f), 800.f);
                    bx = make_float4(x1, y1, x2, y2);
                    float off = (float)c * 4096.0f;
                    ox = make_float4(x1 + off, y1 + off, x2 + off, y2 + off);
                    ar = (ox.z - ox.x) * (ox.w - ox.y);   // area on offset box = reference
                    ssc = sqrtf(s);
                    cl = c;
                    alive = 1;
                    for (int k = 0; k < kn0; ++k) {
                        float4 kb = kobox[k];
                        float xx1 = fmaxf(kb.x, ox.x), yy1 = fmaxf(kb.y, ox.y);
                        float xx2 = fminf(kb.z, ox.z), yy2 = fminf(kb.w, ox.w);
                        float inter = fmaxf(xx2 - xx1, 0.f) * fmaxf(yy2 - yy1, 0.f);
                        float iou = inter / (ar + karea[k] - inter + 1e-9f);
                        if (iou > 0.6f) { alive = 0; break; }
                    }
                }
            }
            sbox[q] = bx; obox[q] = ox; sarea[q] = ar; sscor[q] = ssc; scls[q] = cl;
            if (alive) atomicOr(&aliveW[q >> 5], 1u << (q & 31));
        }
        __syncthreads();
        {   // adjacency rows (j > i only; dead boxes are all-zero -> IoU 0)
            const int i = tid;
            float4 bi = obox[i];
            float ai = sarea[i];
            for (int w = 0; w < 8; ++w) {
                unsigned bb = 0;
                int j0 = w << 5;
                int js = j0 > i + 1 ? j0 : i + 1;
                for (int j = js; j < j0 + 32; ++j) {
                    float4 bj = obox[j];
                    float xx1 = fmaxf(bi.x, bj.x), yy1 = fmaxf(bi.y, bj.y);
                    float xx2 = fminf(bi.z, bj.z), yy2 = fminf(bi.w, bj.w);
                    float inter = fmaxf(xx2 - xx1, 0.f) * fmaxf(yy2 - yy1, 0.f);
                    float iou = inter / (sarea[j] + ai - inter + 1e-9f);
                    if (iou > 0.6f) bb |= 1u << (j & 31);
                }
                adjW[i * 8 + w] = bb;
            }
        }
        __syncthreads();
        if (tid < 64) {   // wave-0 register-bitmask greedy resolve
            const int lane = tid;
            unsigned aw = (lane < 8) ? aliveW[lane] : 0u;
            int kn = kn0;
            while (kn < K_POST) {
                unsigned long long m = __ballot(aw != 0u);
                if (m == 0ull) break;
                int w0 = (int)(__ffsll(m) - 1);
                unsigned word = __shfl(aw, w0);
                int b = __ffs((int)word) - 1;
                int e = (w0 << 5) | b;
                unsigned rw = (lane < 8) ? adjW[e * 8 + lane] : 0u;
                aw &= ~rw;
                if (lane == w0) aw &= ~(1u << b);
                if (lane == 0) {
                    kbox[kn] = sbox[e]; kobox[kn] = obox[e];
                    karea[kn] = sarea[e]; kscor[kn] = sscor[e]; kcls[kn] = scls[e];
                }
                kn++;
            }
            if (lane == 0) { s_keptn = kn; s_done = (kn >= K_POST) ? 1 : 0; }
        }
        __syncthreads();
    }
    const int kn = s_keptn;
    if (tid < K_POST) {
        float4 b = make_float4(0.f, 0.f, 0.f, 0.f);
        float sc = 0.f, cl = 0.f, kp = 0.f;
        if (tid < kn) { b = kbox[tid]; sc = kscor[tid]; cl = (float)kcls[tid]; kp = 1.0f; }
        float* bo = out + (size_t)(img * K_POST + tid) * 4;
        bo[0] = b.x; bo[1] = b.y; bo[2] = b.z; bo[3] = b.w;
        out[N_IMG * K_POST * 4 + img * K_POST + tid] = sc;
        out[N_IMG * K_POST * 5 + img * K_POST + tid] = cl;
        out[N_IMG * K_POST * 6 + img * K_POST + tid] = kp;
    }
}

extern "C" void kernel_launch(void* const* d_in, const int* in_sizes, int n_in,
                              void* d_out, int out_size, void* d_ws, size_t ws_size,
                              hipStream_t stream) {
    const float* loc0 = (const float*)d_in[0];
    const float* cls0 = (const float*)d_in[1];
    const float* reg0 = (const float*)d_in[2];
    const float* ctr0 = (const float*)d_in[3];
    const float* loc1 = (const float*)d_in[4];
    const float* cls1 = (const float*)d_in[5];
    const float* reg1 = (const float*)d_in[6];
    const float* ctr1 = (const float*)d_in[7];
    const float* loc2 = (const float*)d_in[8];
    const float* cls2 = (const float*)d_in[9];
    const float* reg2 = (const float*)d_in[10];
    const float* ctr2 = (const float*)d_in[11];

    char* ws = (char*)d_ws;
    unsigned*           hist  = (unsigned*)(ws + HIST_OFF);
    unsigned*           cnt   = (unsigned*)(ws + CNT_OFF);
    unsigned*           tbin  = (unsigned*)(ws + TBIN_OFF);
    unsigned long long* list  = (unsigned long long*)(ws + LIST_OFF);
    unsigned*           candF = (unsigned*)(ws + CANDF_OFF);
    float*              candS = (float*)(ws + CANDS_OFF);
    float*              out   = (float*)d_out;

    hipMemsetAsync(ws, 0, ZERO_BYTES, stream);

    const dim3 sg(10 * NCG, N_IMG, 3);
    hist_k<<<sg, 256, 0, stream>>>(cls0, cls1, cls2, ctr0, ctr1, ctr2, hist);
    scan_k<<<NPAIR, 256, 0, stream>>>(hist, tbin);
    compact_k<<<sg, 256, 0, stream>>>(cls0, cls1, cls2, ctr0, ctr1, ctr2, tbin, cnt, list);
    select_k<<<NPAIR, 512, 0, stream>>>(cnt, list, candF, candS);
    nms_k<<<N_IMG, 256, 0, stream>>>(loc0, loc1, loc2, reg0, reg1, reg2, candF, candS, out);
}

// Round 4
// 434.749 us; speedup vs baseline: 2.1431x; 1.4063x over previous
//
#include <hip/hip_runtime.h>
#include <math.h>

#define N_IMG 16
#define N_CLS 80
#define K_PRE 1000
#define K_POST 100
#define NPAIR 48
#define NBIN 4096
#define BSHIFT 20          // 12-bit bin = key >> 20  (sign+exp+3 mantissa bits)
#define CAP 4096           // per-pair candidate superset capacity
#define IDXM 0xFFFFFu      // 20-bit packed (loc*80+c) index
#define CHUNK 256
#define BPI 14             // hist/compact blocks per image: lvl0:10, lvl1:3, lvl2:1

// ---- workspace layout (bytes) ----
#define CNT_OFF    0                 // uint[48]            -> 192
#define TBIN_OFF   192               // uint[48]            -> 384
#define ZERO_BYTES 384
#define HIST_OFF   384               // uint[224*4096]      -> 3670400 (+384)
#define LIST_OFF   3670784           // u64[48*4096]        -> 5243648
#define CANDF_OFF  5243648           // uint[48000]         -> 5435648
#define CANDS_OFF  5435648           // float[48000]        -> 5627648

__device__ __forceinline__ float sigm(float x) { return 1.0f / (1.0f + __expf(-x)); }
__device__ __forceinline__ int lvl_hw(int lvl) { return lvl == 0 ? 10000 : (lvl == 1 ? 2500 : 625); }

__device__ __forceinline__ void blk_map(int bx, int& lvl, int& locb) {
    lvl = bx < 10 ? 0 : (bx < 13 ? 1 : 2);
    locb = bx - (lvl == 0 ? 0 : (lvl == 1 ? 10 : 13));
}

// ---------------- scan 1: private-slice histogram (no global atomics) ----------------
__global__ __launch_bounds__(256) void hist_k(
        const float* __restrict__ cls0, const float* __restrict__ cls1, const float* __restrict__ cls2,
        const float* __restrict__ ctr0, const float* __restrict__ ctr1, const float* __restrict__ ctr2,
        unsigned* __restrict__ hist) {
    __shared__ unsigned lh[NBIN];
    const int img = blockIdx.y, bx = blockIdx.x;
    int lvl, locb; blk_map(bx, lvl, locb);
    const float* cls = lvl == 0 ? cls0 : (lvl == 1 ? cls1 : cls2);
    const float* ctr = lvl == 0 ? ctr0 : (lvl == 1 ? ctr1 : ctr2);
    const int HW = lvl_hw(lvl);
    for (int i = threadIdx.x; i < NBIN; i += 256) lh[i] = 0;
    __syncthreads();
    const int fi = locb * 256 + threadIdx.x;     // float4 index
    const int nf4 = HW >> 2;
    const float* clsI = cls + (size_t)img * N_CLS * HW;
    const float* ctrI = ctr + (size_t)img * HW;
    if (fi < nf4) {
        const int base = fi * 4;
        float4 cv = *(const float4*)(ctrI + base);
        float s0 = sigm(cv.x), s1 = sigm(cv.y), s2 = sigm(cv.z), s3 = sigm(cv.w);
        #pragma unroll 8
        for (int c = 0; c < N_CLS; ++c) {
            float4 v = *(const float4*)(clsI + (size_t)c * HW + base);
            float cp;
            cp = sigm(v.x); if (cp > 0.05f) atomicAdd(&lh[__float_as_uint(cp * s0) >> BSHIFT], 1u);
            cp = sigm(v.y); if (cp > 0.05f) atomicAdd(&lh[__float_as_uint(cp * s1) >> BSHIFT], 1u);
            cp = sigm(v.z); if (cp > 0.05f) atomicAdd(&lh[__float_as_uint(cp * s2) >> BSHIFT], 1u);
            cp = sigm(v.w); if (cp > 0.05f) atomicAdd(&lh[__float_as_uint(cp * s3) >> BSHIFT], 1u);
        }
    } else if (fi == nf4) {                      // tail (lvl2: 625 % 4 == 1)
        for (int k = 0; k < (HW & 3); ++k) {
            int loc = nf4 * 4 + k;
            float cs = sigm(ctrI[loc]);
            for (int c = 0; c < N_CLS; ++c) {
                float cp = sigm(clsI[(size_t)c * HW + loc]);
                if (cp > 0.05f) atomicAdd(&lh[__float_as_uint(cp * cs) >> BSHIFT], 1u);
            }
        }
    }
    __syncthreads();
    unsigned* h = hist + (size_t)(img * BPI + bx) * NBIN;
    for (int i = threadIdx.x; i < NBIN; i += 256) h[i] = lh[i];
}

// ---------------- sum slices + threshold bin per pair ----------------
__global__ __launch_bounds__(256) void scan_k(const unsigned* __restrict__ hist, unsigned* __restrict__ tbin) {
    __shared__ unsigned csum[256];
    __shared__ unsigned suf[256];
    __shared__ unsigned res;
    const int p = blockIdx.x, t = threadIdx.x;
    const int img = p / 3, lvl = p % 3;
    const int sb = img * BPI + (lvl == 0 ? 0 : (lvl == 1 ? 10 : 13));
    const int ns = lvl == 0 ? 10 : (lvl == 1 ? 3 : 1);
    const unsigned* h0 = hist + (size_t)sb * NBIN;
    if (t == 0) res = 0;
    unsigned bsum[16];
    unsigned ms = 0;
    for (int j = 0; j < 16; ++j) {
        unsigned a = 0;
        for (int s = 0; s < ns; ++s) a += h0[(size_t)s * NBIN + t * 16 + j];
        bsum[j] = a; ms += a;
    }
    csum[t] = ms;
    __syncthreads();
    if (t == 0) {
        unsigned a = 0;
        for (int i = 255; i >= 0; --i) { suf[i] = a; a += csum[i]; }
    }
    __syncthreads();
    unsigned A = suf[t];
    for (int j = 15; j >= 0; --j) {
        unsigned c = bsum[j];
        if (A < K_PRE && A + c >= K_PRE) res = (unsigned)(t * 16 + j);
        A += c;
    }
    __syncthreads();
    if (t == 0) tbin[p] = res;
}

// ---------------- scan 2: LDS-staged compaction ----------------
__global__ __launch_bounds__(256) void compact_k(
        const float* __restrict__ cls0, const float* __restrict__ cls1, const float* __restrict__ cls2,
        const float* __restrict__ ctr0, const float* __restrict__ ctr1, const float* __restrict__ ctr2,
        const unsigned* __restrict__ tbin, unsigned* __restrict__ cnt, unsigned long long* __restrict__ list) {
    __shared__ unsigned long long buf[CAP];   // 32 KB
    __shared__ unsigned lcnt, gbase;
    const int img = blockIdx.y, bx = blockIdx.x;
    int lvl, locb; blk_map(bx, lvl, locb);
    const float* cls = lvl == 0 ? cls0 : (lvl == 1 ? cls1 : cls2);
    const float* ctr = lvl == 0 ? ctr0 : (lvl == 1 ? ctr1 : ctr2);
    const int HW = lvl_hw(lvl);
    const int p = img * 3 + lvl;
    const unsigned Tb = tbin[p];
    if (threadIdx.x == 0) lcnt = 0;
    __syncthreads();
    const int fi = locb * 256 + threadIdx.x;
    const int nf4 = HW >> 2;
    const float* clsI = cls + (size_t)img * N_CLS * HW;
    const float* ctrI = ctr + (size_t)img * HW;
    if (fi < nf4) {
        const int base = fi * 4;
        float4 cv = *(const float4*)(ctrI + base);
        float s0 = sigm(cv.x), s1 = sigm(cv.y), s2 = sigm(cv.z), s3 = sigm(cv.w);
        #pragma unroll 4
        for (int c = 0; c < N_CLS; ++c) {
            float4 v = *(const float4*)(clsI + (size_t)c * HW + base);
            float css[4] = {s0, s1, s2, s3};
            float cps[4] = {sigm(v.x), sigm(v.y), sigm(v.z), sigm(v.w)};
            #pragma unroll
            for (int k = 0; k < 4; ++k) {
                if (cps[k] > 0.05f) {
                    unsigned key = __float_as_uint(cps[k] * css[k]);
                    if ((key >> BSHIFT) >= Tb) {
                        unsigned slot = atomicAdd(&lcnt, 1u);
                        unsigned idx = (unsigned)((base + k) * N_CLS + c);
                        if (slot < CAP)
                            buf[slot] = ((unsigned long long)key << 20) | (unsigned long long)(IDXM ^ idx);
                    }
                }
            }
        }
    } else if (fi == nf4) {
        for (int k = 0; k < (HW & 3); ++k) {
            int loc = nf4 * 4 + k;
            float cs = sigm(ctrI[loc]);
            for (int c = 0; c < N_CLS; ++c) {
                float cp = sigm(clsI[(size_t)c * HW + loc]);
                if (cp > 0.05f) {
                    unsigned key = __float_as_uint(cp * cs);
                    if ((key >> BSHIFT) >= Tb) {
                        unsigned slot = atomicAdd(&lcnt, 1u);
                        unsigned idx = (unsigned)(loc * N_CLS + c);
                        if (slot < CAP)
                            buf[slot] = ((unsigned long long)key << 20) | (unsigned long long)(IDXM ^ idx);
                    }
                }
            }
        }
    }
    __syncthreads();
    unsigned n = lcnt; if (n > CAP) n = CAP;
    if (threadIdx.x == 0 && n) gbase = atomicAdd(&cnt[p], n);
    __syncthreads();
    if (n) {
        unsigned gb = gbase;
        unsigned long long* lp = list + (size_t)p * CAP;
        for (unsigned i = threadIdx.x; i < n; i += 256) {
            unsigned g = gb + i;
            if (g < CAP) lp[g] = buf[i];
        }
    }
}

// ---------------- exact top-1000 per pair (bitonic on u64, 512 thr) ----------------
__global__ __launch_bounds__(512) void select_k(const unsigned* __restrict__ cnt,
                                                const unsigned long long* __restrict__ list,
                                                unsigned* __restrict__ candF, float* __restrict__ candS) {
    __shared__ unsigned long long sk[CAP];   // 32 KB
    const int p = blockIdx.x, t = threadIdx.x;
    int n = (int)cnt[p]; if (n > CAP) n = CAP;
    const unsigned long long* lp = list + (size_t)p * CAP;
    for (int i = t; i < CAP; i += 512) sk[i] = (i < n) ? lp[i] : 0ull;
    __syncthreads();
    for (int k = 2; k <= CAP; k <<= 1)
        for (int j = k >> 1; j > 0; j >>= 1) {
            for (int i = t; i < CAP; i += 512) {
                int ixj = i ^ j;
                if (ixj > i) {
                    unsigned long long a = sk[i], b = sk[ixj];
                    bool up = ((i & k) == 0);
                    if (up ? (a < b) : (a > b)) { sk[i] = b; sk[ixj] = a; }  // descending
                }
            }
            __syncthreads();
        }
    for (int i = t; i < K_PRE; i += 512) {
        unsigned long long u = sk[i];
        int o = p * K_PRE + i;
        if (u != 0ull) {
            candS[o] = __uint_as_float((unsigned)(u >> 20));
            candF[o] = IDXM ^ (unsigned)(u & IDXM);
        } else { candS[o] = -1.0f; candF[o] = 0u; }
    }
}

// ---------------- merge 3 sorted lists + decode + bitmask greedy NMS ----------------
__global__ __launch_bounds__(256) void nms_k(
        const float* __restrict__ loc0, const float* __restrict__ loc1, const float* __restrict__ loc2,
        const float* __restrict__ reg0, const float* __restrict__ reg1, const float* __restrict__ reg2,
        const unsigned* __restrict__ candF, const float* __restrict__ candS,
        float* __restrict__ out) {
    __shared__ float skey[3000];
    __shared__ unsigned short sidx[3000];
    __shared__ float4 sbox[CHUNK], obox[CHUNK];
    __shared__ float sarea[CHUNK], sscor[CHUNK];
    __shared__ int scls[CHUNK];
    __shared__ unsigned adjW[CHUNK * 8];
    __shared__ unsigned aliveW[8];
    __shared__ float4 kbox[K_POST], kobox[K_POST];
    __shared__ float karea[K_POST], kscor[K_POST];
    __shared__ int kcls[K_POST];
    __shared__ int s_keptn, s_done;
    const int img = blockIdx.x, tid = threadIdx.x;
    if (tid == 0) { s_keptn = 0; s_done = 0; }
    for (int i = tid; i < 3000; i += 256) skey[i] = candS[img * 3000 + i];
    __syncthreads();
    for (int e = tid; e < 3000; e += 256) {
        int l = e >= 2000 ? 2 : (e >= 1000 ? 1 : 0);
        int slot = e - l * 1000;
        float s = skey[e];
        int rank = slot;
        for (int l2 = 0; l2 < 3; ++l2) {
            if (l2 == l) continue;
            const float* kb = skey + l2 * 1000;
            const bool eq = l2 < l;
            int lo = 0, hi = 1000;
            while (lo < hi) {
                int m = (lo + hi) >> 1;
                float v = kb[m];
                bool go = eq ? (v >= s) : (v > s);
                lo = go ? m + 1 : lo;
                hi = go ? hi : m;
            }
            rank += lo;
        }
        sidx[rank] = (unsigned short)e;
    }
    __syncthreads();
    for (int base = 0; base < 3000; base += CHUNK) {
        if (s_done) break;
        const int kn0 = s_keptn;
        if (tid < 8) aliveW[tid] = 0u;
        __syncthreads();
        {
            const int q = tid;
            const int r = base + q;
            float4 bx = make_float4(0.f, 0.f, 0.f, 0.f), ox = bx;
            float ar = 0.f, ssc = 0.f; int cl = 0, alive = 0;
            if (r < 3000) {
                int e = sidx[r];
                int l = e >= 2000 ? 2 : (e >= 1000 ? 1 : 0);
                int slot = e - l * 1000;
                float s = skey[e];
                if (s > 0.f) {
                    int p = img * 3 + l;
                    unsigned fi = candF[p * K_PRE + slot];
                    int loc = (int)(fi / (unsigned)N_CLS);
                    int c = (int)(fi % (unsigned)N_CLS) + 1;
                    const float* locs = l == 0 ? loc0 : (l == 1 ? loc1 : loc2);
                    const float* rg = l == 0 ? reg0 : (l == 1 ? reg1 : reg2);
                    const int HW = lvl_hw(l);
                    const float st = l == 0 ? 8.f : (l == 1 ? 16.f : 32.f);
                    const float* rb = rg + (size_t)img * 4 * HW;
                    float lv = rb[loc] * st, tv = rb[HW + loc] * st;
                    float rv = rb[2 * HW + loc] * st, bv = rb[3 * HW + loc] * st;
                    float x = locs[2 * loc], y = locs[2 * loc + 1];
                    float x1 = fminf(fmaxf(x - lv, 0.f), 800.f);
                    float y1 = fminf(fmaxf(y - tv, 0.f), 800.f);
                    float x2 = fminf(fmaxf(x + rv, 0.f), 800.f);
                    float y2 = fminf(fmaxf(y + bv, 0.f), 800.f);
                    bx = make_float4(x1, y1, x2, y2);
                    float off = (float)c * 4096.0f;
                    ox = make_float4(x1 + off, y1 + off, x2 + off, y2 + off);
                    ar = (ox.z - ox.x) * (ox.w - ox.y);
                    ssc = sqrtf(s);
                    cl = c;
                    alive = 1;
                    for (int k = 0; k < kn0; ++k) {
                        float4 kb = kobox[k];
                        float xx1 = fmaxf(kb.x, ox.x), yy1 = fmaxf(kb.y, ox.y);
                        float xx2 = fminf(kb.z, ox.z), yy2 = fminf(kb.w, ox.w);
                        float inter = fmaxf(xx2 - xx1, 0.f) * fmaxf(yy2 - yy1, 0.f);
                        float iou = inter / (ar + karea[k] - inter + 1e-9f);
                        if (iou > 0.6f) { alive = 0; break; }
                    }
                }
            }
            sbox[q] = bx; obox[q] = ox; sarea[q] = ar; sscor[q] = ssc; scls[q] = cl;
            if (alive) atomicOr(&aliveW[q >> 5], 1u << (q & 31));
        }
        __syncthreads();
        {
            const int i = tid;
            float4 bi = obox[i];
            float ai = sarea[i];
            for (int w = 0; w < 8; ++w) {
                unsigned bb = 0;
                int j0 = w << 5;
                int js = j0 > i + 1 ? j0 : i + 1;
                for (int j = js; j < j0 + 32; ++j) {
                    float4 bj = obox[j];
                    float xx1 = fmaxf(bi.x, bj.x), yy1 = fmaxf(bi.y, bj.y);
                    float xx2 = fminf(bi.z, bj.z), yy2 = fminf(bi.w, bj.w);
                    float inter = fmaxf(xx2 - xx1, 0.f) * fmaxf(yy2 - yy1, 0.f);
                    float iou = inter / (sarea[j] + ai - inter + 1e-9f);
                    if (iou > 0.6f) bb |= 1u << (j & 31);
                }
                adjW[i * 8 + w] = bb;
            }
        }
        __syncthreads();
        if (tid < 64) {
            const int lane = tid;
            unsigned aw = (lane < 8) ? aliveW[lane] : 0u;
            int kn = kn0;
            while (kn < K_POST) {
                unsigned long long m = __ballot(aw != 0u);
                if (m == 0ull) break;
                int w0 = (int)(__ffsll(m) - 1);
                unsigned word = __shfl(aw, w0);
                int b = __ffs((int)word) - 1;
                int e = (w0 << 5) | b;
                unsigned rw = (lane < 8) ? adjW[e * 8 + lane] : 0u;
                aw &= ~rw;
                if (lane == w0) aw &= ~(1u << b);
                if (lane == 0) {
                    kbox[kn] = sbox[e]; kobox[kn] = obox[e];
                    karea[kn] = sarea[e]; kscor[kn] = sscor[e]; kcls[kn] = scls[e];
                }
                kn++;
            }
            if (lane == 0) { s_keptn = kn; s_done = (kn >= K_POST) ? 1 : 0; }
        }
        __syncthreads();
    }
    const int kn = s_keptn;
    if (tid < K_POST) {
        float4 b = make_float4(0.f, 0.f, 0.f, 0.f);
        float sc = 0.f, cl = 0.f, kp = 0.f;
        if (tid < kn) { b = kbox[tid]; sc = kscor[tid]; cl = (float)kcls[tid]; kp = 1.0f; }
        float* bo = out + (size_t)(img * K_POST + tid) * 4;
        bo[0] = b.x; bo[1] = b.y; bo[2] = b.z; bo[3] = b.w;
        out[N_IMG * K_POST * 4 + img * K_POST + tid] = sc;
        out[N_IMG * K_POST * 5 + img * K_POST + tid] = cl;
        out[N_IMG * K_POST * 6 + img * K_POST + tid] = kp;
    }
}

extern "C" void kernel_launch(void* const* d_in, const int* in_sizes, int n_in,
                              void* d_out, int out_size, void* d_ws, size_t ws_size,
                              hipStream_t stream) {
    const float* loc0 = (const float*)d_in[0];
    const float* cls0 = (const float*)d_in[1];
    const float* reg0 = (const float*)d_in[2];
    const float* ctr0 = (const float*)d_in[3];
    const float* loc1 = (const float*)d_in[4];
    const float* cls1 = (const float*)d_in[5];
    const float* reg1 = (const float*)d_in[6];
    const float* ctr1 = (const float*)d_in[7];
    const float* loc2 = (const float*)d_in[8];
    const float* cls2 = (const float*)d_in[9];
    const float* reg2 = (const float*)d_in[10];
    const float* ctr2 = (const float*)d_in[11];

    char* ws = (char*)d_ws;
    unsigned*           cnt   = (unsigned*)(ws + CNT_OFF);
    unsigned*           tbin  = (unsigned*)(ws + TBIN_OFF);
    unsigned*           hist  = (unsigned*)(ws + HIST_OFF);
    unsigned long long* list  = (unsigned long long*)(ws + LIST_OFF);
    unsigned*           candF = (unsigned*)(ws + CANDF_OFF);
    float*              candS = (float*)(ws + CANDS_OFF);
    float*              out   = (float*)d_out;

    hipMemsetAsync(ws, 0, ZERO_BYTES, stream);

    hist_k<<<dim3(BPI, N_IMG), 256, 0, stream>>>(cls0, cls1, cls2, ctr0, ctr1, ctr2, hist);
    scan_k<<<NPAIR, 256, 0, stream>>>(hist, tbin);
    compact_k<<<dim3(BPI, N_IMG), 256, 0, stream>>>(cls0, cls1, cls2, ctr0, ctr1, ctr2, tbin, cnt, list);
    select_k<<<NPAIR, 512, 0, stream>>>(cnt, list, candF, candS);
    nms_k<<<N_IMG, 256, 0, stream>>>(loc0, loc1, loc2, reg0, reg1, reg2, candF, candS, out);
}

// Round 5
// 304.349 us; speedup vs baseline: 3.0614x; 1.4285x over previous
//
#include <hip/hip_runtime.h>
#include <math.h>

#define N_IMG 16
#define N_CLS 80
#define K_PRE 1000
#define K_POST 100
#define NPAIR 48
#define NBIN 4096
#define BSHIFT 20          // 12-bit bin = key >> 20
#define CAP 4096           // per-pair candidate superset capacity
#define IDXM 0xFFFFFu      // 20-bit packed (loc*80+c) index
#define CHUNK 256
#define CPB 20             // classes per block
#define NCG 4              // class groups
#define BPI 56             // blocks per image: lvl0 10*4, lvl1 3*4, lvl2 1*4
#define NWRD (NBIN / 2)    // u16-packed words per slice

// ---- workspace layout (bytes) ----
#define CNT_OFF    0                 // uint[48]                 -> 192
#define TBIN_OFF   192               // uint[48]                 -> 384
#define ZERO_BYTES 384
#define H16_OFF    384               // u32[896*2048] = 7340032  -> 7340416
#define H32_OFF    7340416           // u32[48*4096]  = 786432   -> 8126848
#define LIST_OFF   8126848           // u64[48*4096]  = 1572864  -> 9699712
#define CANDF_OFF  9699712           // uint[48000]              -> 9891712
#define CANDS_OFF  9891712           // float[48000]             -> 10083712

__device__ __forceinline__ float sigm(float x) { return 1.0f / (1.0f + __expf(-x)); }
__device__ __forceinline__ int lvl_hw(int lvl) { return lvl == 0 ? 10000 : (lvl == 1 ? 2500 : 625); }

__device__ __forceinline__ void blk_map(int bx, int& lvl, int& locb, int& cg) {
    if (bx < 40)      { lvl = 0; locb = bx >> 2;        cg = bx & 3; }
    else if (bx < 52) { lvl = 1; locb = (bx - 40) >> 2; cg = bx & 3; }
    else              { lvl = 2; locb = 0;              cg = bx - 52; }
}

// ---------------- scan 1: private u16-slice histogram ----------------
__global__ __launch_bounds__(256) void hist_k(
        const float* __restrict__ cls0, const float* __restrict__ cls1, const float* __restrict__ cls2,
        const float* __restrict__ ctr0, const float* __restrict__ ctr1, const float* __restrict__ ctr2,
        unsigned* __restrict__ h16) {
    __shared__ unsigned lh[NBIN];    // 16 KB
    const int img = blockIdx.y, bx = blockIdx.x;
    int lvl, locb, cg; blk_map(bx, lvl, locb, cg);
    const float* cls = lvl == 0 ? cls0 : (lvl == 1 ? cls1 : cls2);
    const float* ctr = lvl == 0 ? ctr0 : (lvl == 1 ? ctr1 : ctr2);
    const int HW = lvl_hw(lvl);
    for (int i = threadIdx.x; i < NBIN; i += 256) lh[i] = 0;
    __syncthreads();
    const int fi = locb * 256 + threadIdx.x;
    const int nf4 = HW >> 2;
    const float* clsI = cls + (size_t)img * N_CLS * HW + (size_t)cg * CPB * HW;
    const float* ctrI = ctr + (size_t)img * HW;
    if (fi < nf4) {
        const int base = fi * 4;
        float4 cv = *(const float4*)(ctrI + base);
        float s0 = sigm(cv.x), s1 = sigm(cv.y), s2 = sigm(cv.z), s3 = sigm(cv.w);
        #pragma unroll 5
        for (int c = 0; c < CPB; ++c) {
            float4 v = *(const float4*)(clsI + (size_t)c * HW + base);
            float cp;
            cp = sigm(v.x); if (cp > 0.05f) atomicAdd(&lh[__float_as_uint(cp * s0) >> BSHIFT], 1u);
            cp = sigm(v.y); if (cp > 0.05f) atomicAdd(&lh[__float_as_uint(cp * s1) >> BSHIFT], 1u);
            cp = sigm(v.z); if (cp > 0.05f) atomicAdd(&lh[__float_as_uint(cp * s2) >> BSHIFT], 1u);
            cp = sigm(v.w); if (cp > 0.05f) atomicAdd(&lh[__float_as_uint(cp * s3) >> BSHIFT], 1u);
        }
    } else if (fi == nf4) {                      // tail (lvl2: 625 % 4 == 1)
        for (int k = 0; k < (HW & 3); ++k) {
            int loc = nf4 * 4 + k;
            float cs = sigm(ctrI[loc]);
            for (int c = 0; c < CPB; ++c) {
                float cp = sigm(clsI[(size_t)c * HW + loc]);
                if (cp > 0.05f) atomicAdd(&lh[__float_as_uint(cp * cs) >> BSHIFT], 1u);
            }
        }
    }
    __syncthreads();
    unsigned* sp = h16 + (size_t)(img * BPI + bx) * NWRD;
    for (int w = threadIdx.x; w < NWRD; w += 256)
        sp[w] = (lh[2 * w] & 0xFFFFu) | (lh[2 * w + 1] << 16);
}

// ---------------- sum slices -> per-pair u32 histogram ----------------
__global__ __launch_bounds__(256) void reduce_k(const unsigned* __restrict__ h16,
                                                unsigned* __restrict__ h32) {
    const int p = blockIdx.y, chunk = blockIdx.x;
    const int img = p / 3, lvl = p % 3;
    const int sb = img * BPI + (lvl == 0 ? 0 : (lvl == 1 ? 40 : 52));
    const int ns = lvl == 0 ? 40 : (lvl == 1 ? 12 : 4);
    const int w = chunk * 256 + threadIdx.x;     // word index [0,2048)
    const unsigned* s0 = h16 + (size_t)sb * NWRD + w;
    unsigned lo = 0, hi = 0;
    for (int s = 0; s < ns; ++s) {
        unsigned u = s0[(size_t)s * NWRD];
        lo += u & 0xFFFFu; hi += u >> 16;
    }
    h32[(size_t)p * NBIN + 2 * w] = lo;
    h32[(size_t)p * NBIN + 2 * w + 1] = hi;
}

// ---------------- threshold bin per pair ----------------
__global__ __launch_bounds__(256) void scan_k(const unsigned* __restrict__ h32,
                                              unsigned* __restrict__ tbin) {
    __shared__ unsigned hs[NBIN];    // 16 KB
    __shared__ unsigned csum[256];
    __shared__ unsigned suf[256];
    __shared__ unsigned res;
    const int p = blockIdx.x, t = threadIdx.x;
    for (int i = t; i < NBIN; i += 256) hs[i] = h32[(size_t)p * NBIN + i];
    if (t == 0) res = 0;
    __syncthreads();
    unsigned ms = 0;
    for (int j = 0; j < 16; ++j) ms += hs[t * 16 + j];
    csum[t] = ms;
    __syncthreads();
    if (t == 0) {
        unsigned a = 0;
        for (int i = 255; i >= 0; --i) { suf[i] = a; a += csum[i]; }
    }
    __syncthreads();
    unsigned A = suf[t];
    for (int j = 15; j >= 0; --j) {
        unsigned c = hs[t * 16 + j];
        if (A < K_PRE && A + c >= K_PRE) res = (unsigned)(t * 16 + j);
        A += c;
    }
    __syncthreads();
    if (t == 0) tbin[p] = res;
}

// ---------------- scan 2: LDS-staged compaction ----------------
__global__ __launch_bounds__(256) void compact_k(
        const float* __restrict__ cls0, const float* __restrict__ cls1, const float* __restrict__ cls2,
        const float* __restrict__ ctr0, const float* __restrict__ ctr1, const float* __restrict__ ctr2,
        const unsigned* __restrict__ tbin, unsigned* __restrict__ cnt, unsigned long long* __restrict__ list) {
    __shared__ unsigned long long buf[CAP];   // 32 KB
    __shared__ unsigned lcnt, gbase;
    const int img = blockIdx.y, bx = blockIdx.x;
    int lvl, locb, cg; blk_map(bx, lvl, locb, cg);
    const float* cls = lvl == 0 ? cls0 : (lvl == 1 ? cls1 : cls2);
    const float* ctr = lvl == 0 ? ctr0 : (lvl == 1 ? ctr1 : ctr2);
    const int HW = lvl_hw(lvl);
    const int p = img * 3 + lvl;
    const unsigned Tb = tbin[p];
    if (threadIdx.x == 0) lcnt = 0;
    __syncthreads();
    const int fi = locb * 256 + threadIdx.x;
    const int nf4 = HW >> 2;
    const float* clsI = cls + (size_t)img * N_CLS * HW + (size_t)cg * CPB * HW;
    const float* ctrI = ctr + (size_t)img * HW;
    const int c0 = cg * CPB;
    if (fi < nf4) {
        const int base = fi * 4;
        float4 cv = *(const float4*)(ctrI + base);
        float css[4] = {sigm(cv.x), sigm(cv.y), sigm(cv.z), sigm(cv.w)};
        #pragma unroll 5
        for (int c = 0; c < CPB; ++c) {
            float4 v = *(const float4*)(clsI + (size_t)c * HW + base);
            float cps[4] = {sigm(v.x), sigm(v.y), sigm(v.z), sigm(v.w)};
            #pragma unroll
            for (int k = 0; k < 4; ++k) {
                if (cps[k] > 0.05f) {
                    unsigned key = __float_as_uint(cps[k] * css[k]);
                    if ((key >> BSHIFT) >= Tb) {
                        unsigned slot = atomicAdd(&lcnt, 1u);
                        unsigned idx = (unsigned)((base + k) * N_CLS + c0 + c);
                        if (slot < CAP)
                            buf[slot] = ((unsigned long long)key << 20) | (unsigned long long)(IDXM ^ idx);
                    }
                }
            }
        }
    } else if (fi == nf4) {
        for (int k = 0; k < (HW & 3); ++k) {
            int loc = nf4 * 4 + k;
            float cs = sigm(ctrI[loc]);
            for (int c = 0; c < CPB; ++c) {
                float cp = sigm(clsI[(size_t)c * HW + loc]);
                if (cp > 0.05f) {
                    unsigned key = __float_as_uint(cp * cs);
                    if ((key >> BSHIFT) >= Tb) {
                        unsigned slot = atomicAdd(&lcnt, 1u);
                        unsigned idx = (unsigned)(loc * N_CLS + c0 + c);
                        if (slot < CAP)
                            buf[slot] = ((unsigned long long)key << 20) | (unsigned long long)(IDXM ^ idx);
                    }
                }
            }
        }
    }
    __syncthreads();
    unsigned n = lcnt; if (n > CAP) n = CAP;
    if (threadIdx.x == 0 && n) gbase = atomicAdd(&cnt[p], n);
    __syncthreads();
    if (n) {
        unsigned gb = gbase;
        unsigned long long* lp = list + (size_t)p * CAP;
        for (unsigned i = threadIdx.x; i < n; i += 256) {
            unsigned g = gb + i;
            if (g < CAP) lp[g] = buf[i];
        }
    }
}

// ---------------- exact top-1000 per pair (dynamic bitonic, 1024 thr) ----------------
__global__ __launch_bounds__(1024) void select_k(const unsigned* __restrict__ cnt,
                                                 const unsigned long long* __restrict__ list,
                                                 unsigned* __restrict__ candF, float* __restrict__ candS) {
    __shared__ unsigned long long sk[CAP];   // 32 KB
    const int p = blockIdx.x, t = threadIdx.x;
    int n = (int)cnt[p]; if (n > CAP) n = CAP;
    int m = 1024; while (m < n) m <<= 1;
    const unsigned long long* lp = list + (size_t)p * CAP;
    for (int i = t; i < m; i += 1024) sk[i] = (i < n) ? lp[i] : 0ull;
    __syncthreads();
    for (int k = 2; k <= m; k <<= 1)
        for (int j = k >> 1; j > 0; j >>= 1) {
            for (int i = t; i < m; i += 1024) {
                int ixj = i ^ j;
                if (ixj > i) {
                    unsigned long long a = sk[i], b = sk[ixj];
                    bool up = ((i & k) == 0);
                    if (up ? (a < b) : (a > b)) { sk[i] = b; sk[ixj] = a; }  // descending
                }
            }
            __syncthreads();
        }
    if (t < K_PRE) {
        unsigned long long u = sk[t];
        int o = p * K_PRE + t;
        if (u != 0ull) {
            candS[o] = __uint_as_float((unsigned)(u >> 20));
            candF[o] = IDXM ^ (unsigned)(u & IDXM);
        } else { candS[o] = -1.0f; candF[o] = 0u; }
    }
}

// ---------------- merge 3 sorted lists + decode + bitmask greedy NMS ----------------
__global__ __launch_bounds__(256) void nms_k(
        const float* __restrict__ loc0, const float* __restrict__ loc1, const float* __restrict__ loc2,
        const float* __restrict__ reg0, const float* __restrict__ reg1, const float* __restrict__ reg2,
        const unsigned* __restrict__ candF, const float* __restrict__ candS,
        float* __restrict__ out) {
    __shared__ float skey[3000];
    __shared__ unsigned short sidx[3000];
    __shared__ float4 sbox[CHUNK], obox[CHUNK];
    __shared__ float sarea[CHUNK], sscor[CHUNK];
    __shared__ int scls[CHUNK];
    __shared__ unsigned adjW[CHUNK * 8];
    __shared__ unsigned aliveW[8];
    __shared__ float4 kbox[K_POST], kobox[K_POST];
    __shared__ float karea[K_POST], kscor[K_POST];
    __shared__ int kcls[K_POST];
    __shared__ int s_keptn, s_done;
    const int img = blockIdx.x, tid = threadIdx.x;
    if (tid == 0) { s_keptn = 0; s_done = 0; }
    for (int i = tid; i < 3000; i += 256) skey[i] = candS[img * 3000 + i];
    __syncthreads();
    for (int e = tid; e < 3000; e += 256) {
        int l = e >= 2000 ? 2 : (e >= 1000 ? 1 : 0);
        int slot = e - l * 1000;
        float s = skey[e];
        int rank = slot;
        for (int l2 = 0; l2 < 3; ++l2) {
            if (l2 == l) continue;
            const float* kb = skey + l2 * 1000;
            const bool eq = l2 < l;
            int lo = 0, hi = 1000;
            while (lo < hi) {
                int m = (lo + hi) >> 1;
                float v = kb[m];
                bool go = eq ? (v >= s) : (v > s);
                lo = go ? m + 1 : lo;
                hi = go ? hi : m;
            }
            rank += lo;
        }
        sidx[rank] = (unsigned short)e;
    }
    __syncthreads();
    for (int base = 0; base < 3000; base += CHUNK) {
        if (s_done) break;
        const int kn0 = s_keptn;
        if (tid < 8) aliveW[tid] = 0u;
        __syncthreads();
        {
            const int q = tid;
            const int r = base + q;
            float4 bx = make_float4(0.f, 0.f, 0.f, 0.f), ox = bx;
            float ar = 0.f, ssc = 0.f; int cl = 0, alive = 0;
            if (r < 3000) {
                int e = sidx[r];
                int l = e >= 2000 ? 2 : (e >= 1000 ? 1 : 0);
                int slot = e - l * 1000;
                float s = skey[e];
                if (s > 0.f) {
                    int p = img * 3 + l;
                    unsigned fi = candF[p * K_PRE + slot];
                    int loc = (int)(fi / (unsigned)N_CLS);
                    int c = (int)(fi % (unsigned)N_CLS) + 1;
                    const float* locs = l == 0 ? loc0 : (l == 1 ? loc1 : loc2);
                    const float* rg = l == 0 ? reg0 : (l == 1 ? reg1 : reg2);
                    const int HW = lvl_hw(l);
                    const float st = l == 0 ? 8.f : (l == 1 ? 16.f : 32.f);
                    const float* rb = rg + (size_t)img * 4 * HW;
                    float lv = rb[loc] * st, tv = rb[HW + loc] * st;
                    float rv = rb[2 * HW + loc] * st, bv = rb[3 * HW + loc] * st;
                    float x = locs[2 * loc], y = locs[2 * loc + 1];
                    float x1 = fminf(fmaxf(x - lv, 0.f), 800.f);
                    float y1 = fminf(fmaxf(y - tv, 0.f), 800.f);
                    float x2 = fminf(fmaxf(x + rv, 0.f), 800.f);
                    float y2 = fminf(fmaxf(y + bv, 0.f), 800.f);
                    bx = make_float4(x1, y1, x2, y2);
                    float off = (float)c * 4096.0f;
                    ox = make_float4(x1 + off, y1 + off, x2 + off, y2 + off);
                    ar = (ox.z - ox.x) * (ox.w - ox.y);
                    ssc = sqrtf(s);
                    cl = c;
                    alive = 1;
                    for (int k = 0; k < kn0; ++k) {
                        float4 kb = kobox[k];
                        float xx1 = fmaxf(kb.x, ox.x), yy1 = fmaxf(kb.y, ox.y);
                        float xx2 = fminf(kb.z, ox.z), yy2 = fminf(kb.w, ox.w);
                        float inter = fmaxf(xx2 - xx1, 0.f) * fmaxf(yy2 - yy1, 0.f);
                        float iou = inter / (ar + karea[k] - inter + 1e-9f);
                        if (iou > 0.6f) { alive = 0; break; }
                    }
                }
            }
            sbox[q] = bx; obox[q] = ox; sarea[q] = ar; sscor[q] = ssc; scls[q] = cl;
            if (alive) atomicOr(&aliveW[q >> 5], 1u << (q & 31));
        }
        __syncthreads();
        {
            const int i = tid;
            float4 bi = obox[i];
            float ai = sarea[i];
            for (int w = 0; w < 8; ++w) {
                unsigned bb = 0;
                int j0 = w << 5;
                int js = j0 > i + 1 ? j0 : i + 1;
                for (int j = js; j < j0 + 32; ++j) {
                    float4 bj = obox[j];
                    float xx1 = fmaxf(bi.x, bj.x), yy1 = fmaxf(bi.y, bj.y);
                    float xx2 = fminf(bi.z, bj.z), yy2 = fminf(bi.w, bj.w);
                    float inter = fmaxf(xx2 - xx1, 0.f) * fmaxf(yy2 - yy1, 0.f);
                    float iou = inter / (sarea[j] + ai - inter + 1e-9f);
                    if (iou > 0.6f) bb |= 1u << (j & 31);
                }
                adjW[i * 8 + w] = bb;
            }
        }
        __syncthreads();
        if (tid < 64) {
            const int lane = tid;
            unsigned aw = (lane < 8) ? aliveW[lane] : 0u;
            int kn = kn0;
            while (kn < K_POST) {
                unsigned long long m = __ballot(aw != 0u);
                if (m == 0ull) break;
                int w0 = (int)(__ffsll(m) - 1);
                unsigned word = __shfl(aw, w0);
                int b = __ffs((int)word) - 1;
                int e = (w0 << 5) | b;
                unsigned rw = (lane < 8) ? adjW[e * 8 + lane] : 0u;
                aw &= ~rw;
                if (lane == w0) aw &= ~(1u << b);
                if (lane == 0) {
                    kbox[kn] = sbox[e]; kobox[kn] = obox[e];
                    karea[kn] = sarea[e]; kscor[kn] = sscor[e]; kcls[kn] = scls[e];
                }
                kn++;
            }
            if (lane == 0) { s_keptn = kn; s_done = (kn >= K_POST) ? 1 : 0; }
        }
        __syncthreads();
    }
    const int kn = s_keptn;
    if (tid < K_POST) {
        float4 b = make_float4(0.f, 0.f, 0.f, 0.f);
        float sc = 0.f, cl = 0.f, kp = 0.f;
        if (tid < kn) { b = kbox[tid]; sc = kscor[tid]; cl = (float)kcls[tid]; kp = 1.0f; }
        float* bo = out + (size_t)(img * K_POST + tid) * 4;
        bo[0] = b.x; bo[1] = b.y; bo[2] = b.z; bo[3] = b.w;
        out[N_IMG * K_POST * 4 + img * K_POST + tid] = sc;
        out[N_IMG * K_POST * 5 + img * K_POST + tid] = cl;
        out[N_IMG * K_POST * 6 + img * K_POST + tid] = kp;
    }
}

extern "C" void kernel_launch(void* const* d_in, const int* in_sizes, int n_in,
                              void* d_out, int out_size, void* d_ws, size_t ws_size,
                              hipStream_t stream) {
    const float* loc0 = (const float*)d_in[0];
    const float* cls0 = (const float*)d_in[1];
    const float* reg0 = (const float*)d_in[2];
    const float* ctr0 = (const float*)d_in[3];
    const float* loc1 = (const float*)d_in[4];
    const float* cls1 = (const float*)d_in[5];
    const float* reg1 = (const float*)d_in[6];
    const float* ctr1 = (const float*)d_in[7];
    const float* loc2 = (const float*)d_in[8];
    const float* cls2 = (const float*)d_in[9];
    const float* reg2 = (const float*)d_in[10];
    const float* ctr2 = (const float*)d_in[11];

    char* ws = (char*)d_ws;
    unsigned*           cnt   = (unsigned*)(ws + CNT_OFF);
    unsigned*           tbin  = (unsigned*)(ws + TBIN_OFF);
    unsigned*           h16   = (unsigned*)(ws + H16_OFF);
    unsigned*           h32   = (unsigned*)(ws + H32_OFF);
    unsigned long long* list  = (unsigned long long*)(ws + LIST_OFF);
    unsigned*           candF = (unsigned*)(ws + CANDF_OFF);
    float*              candS = (float*)(ws + CANDS_OFF);
    float*              out   = (float*)d_out;

    hipMemsetAsync(ws, 0, ZERO_BYTES, stream);

    hist_k<<<dim3(BPI, N_IMG), 256, 0, stream>>>(cls0, cls1, cls2, ctr0, ctr1, ctr2, h16);
    reduce_k<<<dim3(8, NPAIR), 256, 0, stream>>>(h16, h32);
    scan_k<<<NPAIR, 256, 0, stream>>>(h32, tbin);
    compact_k<<<dim3(BPI, N_IMG), 256, 0, stream>>>(cls0, cls1, cls2, ctr0, ctr1, ctr2, tbin, cnt, list);
    select_k<<<NPAIR, 1024, 0, stream>>>(cnt, list, candF, candS);
    nms_k<<<N_IMG, 256, 0, stream>>>(loc0, loc1, loc2, reg0, reg1, reg2, candF, candS, out);
}

// Round 6
// 284.374 us; speedup vs baseline: 3.2764x; 1.0702x over previous
//
#include <hip/hip_runtime.h>
#include <math.h>

#define N_IMG 16
#define N_CLS 80
#define K_PRE 1000
#define K_POST 100
#define NPAIR 48
#define NBIN 4096
#define BSHIFT 20          // 12-bit bin = key >> 20
#define CAP 4096
#define IDXM 0xFFFFFu      // 20-bit packed (loc*80+c) index
#define CHUNK 256
#define CPB 20             // classes per block
#define BPI 56             // blocks per image: lvl0 10*4, lvl1 3*4, lvl2 1*4
#define NWRD (NBIN / 2)

// ---- workspace layout (bytes) ----
#define CNT_OFF    0                 // uint[48]                 -> 192
#define TBIN_OFF   192               // uint[48]                 -> 384
#define ZERO_BYTES 384
#define H16_OFF    384               // u32[896*2048]            -> 7340416
#define H32_OFF    7340416           // u32[48*4096]             -> 8126848
#define LIST_OFF   8126848           // u64[48*4096]             -> 9699712
#define CANDF_OFF  9699712           // uint[48000]              -> 9891712
#define CANDS_OFF  9891712           // float[48000]             -> 10083712
#define DBOX_OFF   10083712          // float4[48000] (16B-al)   -> 10851712
#define DCLS_OFF   10851712          // int[48000]               -> 11043712

__device__ __forceinline__ float sigm(float x) { return 1.0f / (1.0f + __expf(-x)); }
__device__ __forceinline__ int lvl_hw(int lvl) { return lvl == 0 ? 10000 : (lvl == 1 ? 2500 : 625); }

__device__ __forceinline__ void blk_map(int bx, int& lvl, int& locb, int& cg) {
    if (bx < 40)      { lvl = 0; locb = bx >> 2;        cg = bx & 3; }
    else if (bx < 52) { lvl = 1; locb = (bx - 40) >> 2; cg = bx & 3; }
    else              { lvl = 2; locb = 0;              cg = bx - 52; }
}

// ---------------- scan 1: private u16-slice histogram ----------------
__global__ __launch_bounds__(256) void hist_k(
        const float* __restrict__ cls0, const float* __restrict__ cls1, const float* __restrict__ cls2,
        const float* __restrict__ ctr0, const float* __restrict__ ctr1, const float* __restrict__ ctr2,
        unsigned* __restrict__ h16) {
    __shared__ unsigned lh[NBIN];
    const int img = blockIdx.y, bx = blockIdx.x;
    int lvl, locb, cg; blk_map(bx, lvl, locb, cg);
    const float* cls = lvl == 0 ? cls0 : (lvl == 1 ? cls1 : cls2);
    const float* ctr = lvl == 0 ? ctr0 : (lvl == 1 ? ctr1 : ctr2);
    const int HW = lvl_hw(lvl);
    for (int i = threadIdx.x; i < NBIN; i += 256) lh[i] = 0;
    __syncthreads();
    const int fi = locb * 256 + threadIdx.x;
    const int nf4 = HW >> 2;
    const float* clsI = cls + (size_t)img * N_CLS * HW + (size_t)cg * CPB * HW;
    const float* ctrI = ctr + (size_t)img * HW;
    if (fi < nf4) {
        const int base = fi * 4;
        float4 cv = *(const float4*)(ctrI + base);
        float s0 = sigm(cv.x), s1 = sigm(cv.y), s2 = sigm(cv.z), s3 = sigm(cv.w);
        #pragma unroll 5
        for (int c = 0; c < CPB; ++c) {
            float4 v = *(const float4*)(clsI + (size_t)c * HW + base);
            float cp;
            cp = sigm(v.x); if (cp > 0.05f) atomicAdd(&lh[__float_as_uint(cp * s0) >> BSHIFT], 1u);
            cp = sigm(v.y); if (cp > 0.05f) atomicAdd(&lh[__float_as_uint(cp * s1) >> BSHIFT], 1u);
            cp = sigm(v.z); if (cp > 0.05f) atomicAdd(&lh[__float_as_uint(cp * s2) >> BSHIFT], 1u);
            cp = sigm(v.w); if (cp > 0.05f) atomicAdd(&lh[__float_as_uint(cp * s3) >> BSHIFT], 1u);
        }
    } else if (fi == nf4) {
        for (int k = 0; k < (HW & 3); ++k) {
            int loc = nf4 * 4 + k;
            float cs = sigm(ctrI[loc]);
            for (int c = 0; c < CPB; ++c) {
                float cp = sigm(clsI[(size_t)c * HW + loc]);
                if (cp > 0.05f) atomicAdd(&lh[__float_as_uint(cp * cs) >> BSHIFT], 1u);
            }
        }
    }
    __syncthreads();
    unsigned* sp = h16 + (size_t)(img * BPI + bx) * NWRD;
    for (int w = threadIdx.x; w < NWRD; w += 256)
        sp[w] = (lh[2 * w] & 0xFFFFu) | (lh[2 * w + 1] << 16);
}

// ---------------- sum slices -> per-pair u32 histogram ----------------
__global__ __launch_bounds__(256) void reduce_k(const unsigned* __restrict__ h16,
                                                unsigned* __restrict__ h32) {
    const int p = blockIdx.y, chunk = blockIdx.x;
    const int img = p / 3, lvl = p % 3;
    const int sb = img * BPI + (lvl == 0 ? 0 : (lvl == 1 ? 40 : 52));
    const int ns = lvl == 0 ? 40 : (lvl == 1 ? 12 : 4);
    const int w = chunk * 256 + threadIdx.x;
    const unsigned* s0 = h16 + (size_t)sb * NWRD + w;
    unsigned lo = 0, hi = 0;
    for (int s = 0; s < ns; ++s) {
        unsigned u = s0[(size_t)s * NWRD];
        lo += u & 0xFFFFu; hi += u >> 16;
    }
    h32[(size_t)p * NBIN + 2 * w] = lo;
    h32[(size_t)p * NBIN + 2 * w + 1] = hi;
}

// ---------------- threshold bin per pair ----------------
__global__ __launch_bounds__(256) void scan_k(const unsigned* __restrict__ h32,
                                              unsigned* __restrict__ tbin) {
    __shared__ unsigned hs[NBIN];
    __shared__ unsigned csum[256];
    __shared__ unsigned suf[256];
    __shared__ unsigned res;
    const int p = blockIdx.x, t = threadIdx.x;
    for (int i = t; i < NBIN; i += 256) hs[i] = h32[(size_t)p * NBIN + i];
    if (t == 0) res = 0;
    __syncthreads();
    unsigned ms = 0;
    for (int j = 0; j < 16; ++j) ms += hs[t * 16 + j];
    csum[t] = ms;
    __syncthreads();
    if (t == 0) {
        unsigned a = 0;
        for (int i = 255; i >= 0; --i) { suf[i] = a; a += csum[i]; }
    }
    __syncthreads();
    unsigned A = suf[t];
    for (int j = 15; j >= 0; --j) {
        unsigned c = hs[t * 16 + j];
        if (A < K_PRE && A + c >= K_PRE) res = (unsigned)(t * 16 + j);
        A += c;
    }
    __syncthreads();
    if (t == 0) tbin[p] = res;
}

// ---------------- scan 2: LDS-staged compaction ----------------
__global__ __launch_bounds__(256) void compact_k(
        const float* __restrict__ cls0, const float* __restrict__ cls1, const float* __restrict__ cls2,
        const float* __restrict__ ctr0, const float* __restrict__ ctr1, const float* __restrict__ ctr2,
        const unsigned* __restrict__ tbin, unsigned* __restrict__ cnt, unsigned long long* __restrict__ list) {
    __shared__ unsigned long long buf[CAP];
    __shared__ unsigned lcnt, gbase;
    const int img = blockIdx.y, bx = blockIdx.x;
    int lvl, locb, cg; blk_map(bx, lvl, locb, cg);
    const float* cls = lvl == 0 ? cls0 : (lvl == 1 ? cls1 : cls2);
    const float* ctr = lvl == 0 ? ctr0 : (lvl == 1 ? ctr1 : ctr2);
    const int HW = lvl_hw(lvl);
    const int p = img * 3 + lvl;
    const unsigned Tb = tbin[p];
    if (threadIdx.x == 0) lcnt = 0;
    __syncthreads();
    const int fi = locb * 256 + threadIdx.x;
    const int nf4 = HW >> 2;
    const float* clsI = cls + (size_t)img * N_CLS * HW + (size_t)cg * CPB * HW;
    const float* ctrI = ctr + (size_t)img * HW;
    const int c0 = cg * CPB;
    if (fi < nf4) {
        const int base = fi * 4;
        float4 cv = *(const float4*)(ctrI + base);
        float css[4] = {sigm(cv.x), sigm(cv.y), sigm(cv.z), sigm(cv.w)};
        #pragma unroll 5
        for (int c = 0; c < CPB; ++c) {
            float4 v = *(const float4*)(clsI + (size_t)c * HW + base);
            float cps[4] = {sigm(v.x), sigm(v.y), sigm(v.z), sigm(v.w)};
            #pragma unroll
            for (int k = 0; k < 4; ++k) {
                if (cps[k] > 0.05f) {
                    unsigned key = __float_as_uint(cps[k] * css[k]);
                    if ((key >> BSHIFT) >= Tb) {
                        unsigned slot = atomicAdd(&lcnt, 1u);
                        unsigned idx = (unsigned)((base + k) * N_CLS + c0 + c);
                        if (slot < CAP)
                            buf[slot] = ((unsigned long long)key << 20) | (unsigned long long)(IDXM ^ idx);
                    }
                }
            }
        }
    } else if (fi == nf4) {
        for (int k = 0; k < (HW & 3); ++k) {
            int loc = nf4 * 4 + k;
            float cs = sigm(ctrI[loc]);
            for (int c = 0; c < CPB; ++c) {
                float cp = sigm(clsI[(size_t)c * HW + loc]);
                if (cp > 0.05f) {
                    unsigned key = __float_as_uint(cp * cs);
                    if ((key >> BSHIFT) >= Tb) {
                        unsigned slot = atomicAdd(&lcnt, 1u);
                        unsigned idx = (unsigned)(loc * N_CLS + c0 + c);
                        if (slot < CAP)
                            buf[slot] = ((unsigned long long)key << 20) | (unsigned long long)(IDXM ^ idx);
                    }
                }
            }
        }
    }
    __syncthreads();
    unsigned n = lcnt; if (n > CAP) n = CAP;
    if (threadIdx.x == 0 && n) gbase = atomicAdd(&cnt[p], n);
    __syncthreads();
    if (n) {
        unsigned gb = gbase;
        unsigned long long* lp = list + (size_t)p * CAP;
        for (unsigned i = threadIdx.x; i < n; i += 256) {
            unsigned g = gb + i;
            if (g < CAP) lp[g] = buf[i];
        }
    }
}

// ---------------- exact top-1000 per pair (dynamic bitonic, 1024 thr) ----------------
__global__ __launch_bounds__(1024) void select_k(const unsigned* __restrict__ cnt,
                                                 const unsigned long long* __restrict__ list,
                                                 unsigned* __restrict__ candF, float* __restrict__ candS) {
    __shared__ unsigned long long sk[CAP];
    const int p = blockIdx.x, t = threadIdx.x;
    int n = (int)cnt[p]; if (n > CAP) n = CAP;
    int m = 1024; while (m < n) m <<= 1;
    const unsigned long long* lp = list + (size_t)p * CAP;
    for (int i = t; i < m; i += 1024) sk[i] = (i < n) ? lp[i] : 0ull;
    __syncthreads();
    for (int k = 2; k <= m; k <<= 1)
        for (int j = k >> 1; j > 0; j >>= 1) {
            for (int i = t; i < m; i += 1024) {
                int ixj = i ^ j;
                if (ixj > i) {
                    unsigned long long a = sk[i], b = sk[ixj];
                    bool up = ((i & k) == 0);
                    if (up ? (a < b) : (a > b)) { sk[i] = b; sk[ixj] = a; }
                }
            }
            __syncthreads();
        }
    if (t < K_PRE) {
        unsigned long long u = sk[t];
        int o = p * K_PRE + t;
        if (u != 0ull) {
            candS[o] = __uint_as_float((unsigned)(u >> 20));
            candF[o] = IDXM ^ (unsigned)(u & IDXM);
        } else { candS[o] = -1.0f; candF[o] = 0u; }
    }
}

// ---------------- parallel box decode (removes pointer-chase from nms) ----------------
__global__ __launch_bounds__(256) void decode_k(
        const float* __restrict__ loc0, const float* __restrict__ loc1, const float* __restrict__ loc2,
        const float* __restrict__ reg0, const float* __restrict__ reg1, const float* __restrict__ reg2,
        const unsigned* __restrict__ candF, const float* __restrict__ candS,
        float4* __restrict__ dbox, int* __restrict__ dcls) {
    int i = blockIdx.x * blockDim.x + threadIdx.x;
    if (i >= NPAIR * K_PRE) return;
    int p = i / K_PRE, slot = i % K_PRE;
    int img = p / 3, lvl = p % 3;
    int o = img * 3000 + lvl * K_PRE + slot;
    float s = candS[i];
    if (!(s > 0.0f)) { dbox[o] = make_float4(0.f, 0.f, 0.f, 0.f); dcls[o] = 0; return; }
    const float* locs = lvl == 0 ? loc0 : (lvl == 1 ? loc1 : loc2);
    const float* rg = lvl == 0 ? reg0 : (lvl == 1 ? reg1 : reg2);
    const int HW = lvl_hw(lvl);
    const float st = lvl == 0 ? 8.f : (lvl == 1 ? 16.f : 32.f);
    unsigned fi = candF[i];
    int loc = (int)(fi / (unsigned)N_CLS);
    int c = (int)(fi % (unsigned)N_CLS) + 1;
    const float* rb = rg + (size_t)img * 4 * HW;
    float lv = rb[loc] * st, tv = rb[HW + loc] * st;
    float rv = rb[2 * HW + loc] * st, bv = rb[3 * HW + loc] * st;
    float x = locs[2 * loc], y = locs[2 * loc + 1];
    float x1 = fminf(fmaxf(x - lv, 0.f), 800.f);
    float y1 = fminf(fmaxf(y - tv, 0.f), 800.f);
    float x2 = fminf(fmaxf(x + rv, 0.f), 800.f);
    float y2 = fminf(fmaxf(y + bv, 0.f), 800.f);
    dbox[o] = make_float4(x1, y1, x2, y2);
    dcls[o] = c;
}

// ---------------- merge 3 sorted lists + bitmask greedy NMS (1024 thr) ----------------
__global__ __launch_bounds__(1024) void nms_k(
        const float4* __restrict__ dbox, const int* __restrict__ dcls,
        const float* __restrict__ candS, float* __restrict__ out) {
    __shared__ float skey[3000];
    __shared__ unsigned short sidx[3000];
    __shared__ float4 sbox[CHUNK], obox[CHUNK];
    __shared__ float sarea[CHUNK], sscor[CHUNK];
    __shared__ int scls[CHUNK];
    __shared__ unsigned adjW[CHUNK * 8];
    __shared__ unsigned aliveW[8];
    __shared__ float4 kbox[K_POST], kobox[K_POST];
    __shared__ float karea[K_POST], kscor[K_POST];
    __shared__ int kcls[K_POST];
    __shared__ int s_keptn, s_done;
    const int img = blockIdx.x, tid = threadIdx.x;
    if (tid == 0) { s_keptn = 0; s_done = 0; }
    for (int i = tid; i < 3000; i += 1024) skey[i] = candS[img * 3000 + i];
    __syncthreads();
    // rank-merge: order = (score desc, lvl, slot) == reference concat + argmax tie rule
    for (int e = tid; e < 3000; e += 1024) {
        int l = e >= 2000 ? 2 : (e >= 1000 ? 1 : 0);
        int slot = e - l * 1000;
        float s = skey[e];
        int rank = slot;
        for (int l2 = 0; l2 < 3; ++l2) {
            if (l2 == l) continue;
            const float* kb = skey + l2 * 1000;
            const bool eq = l2 < l;
            int lo = 0, hi = 1000;
            while (lo < hi) {
                int m = (lo + hi) >> 1;
                float v = kb[m];
                bool go = eq ? (v >= s) : (v > s);
                lo = go ? m + 1 : lo;
                hi = go ? hi : m;
            }
            rank += lo;
        }
        sidx[rank] = (unsigned short)e;
    }
    __syncthreads();
    for (int base = 0; base < 3000; base += CHUNK) {
        if (s_done) break;
        const int kn0 = s_keptn;
        if (tid < 8) aliveW[tid] = 0u;
        __syncthreads();
        if (tid < CHUNK) {   // load chunk (coalesced-ish global reads) + filter vs kept
            const int q = tid;
            const int r = base + q;
            float4 bx = make_float4(0.f, 0.f, 0.f, 0.f), ox = bx;
            float ar = 0.f, ssc = 0.f; int cl = 0, alive = 0;
            if (r < 3000) {
                int e = sidx[r];
                float s = skey[e];
                if (s > 0.f) {
                    bx = dbox[img * 3000 + e];
                    cl = dcls[img * 3000 + e];
                    float off = (float)cl * 4096.0f;
                    ox = make_float4(bx.x + off, bx.y + off, bx.z + off, bx.w + off);
                    ar = (ox.z - ox.x) * (ox.w - ox.y);
                    ssc = sqrtf(s);
                    alive = 1;
                    for (int k = 0; k < kn0; ++k) {
                        float4 kb = kobox[k];
                        float xx1 = fmaxf(kb.x, ox.x), yy1 = fmaxf(kb.y, ox.y);
                        float xx2 = fminf(kb.z, ox.z), yy2 = fminf(kb.w, ox.w);
                        float inter = fmaxf(xx2 - xx1, 0.f) * fmaxf(yy2 - yy1, 0.f);
                        float iou = inter / (ar + karea[k] - inter + 1e-9f);
                        if (iou > 0.6f) { alive = 0; break; }
                    }
                }
            }
            sbox[q] = bx; obox[q] = ox; sarea[q] = ar; sscor[q] = ssc; scls[q] = cl;
            if (alive) atomicOr(&aliveW[q >> 5], 1u << (q & 31));
        }
        __syncthreads();
        {   // adjacency rows: 4 groups × 2 words each (j > i only)
            const int g = tid >> 8;          // 0..3
            const int i = tid & 255;
            float4 bi = obox[i];
            float ai = sarea[i];
            #pragma unroll
            for (int ww = 0; ww < 2; ++ww) {
                const int w = g * 2 + ww;
                unsigned bb = 0;
                int j0 = w << 5;
                int js = j0 > i + 1 ? j0 : i + 1;
                for (int j = js; j < j0 + 32; ++j) {
                    float4 bj = obox[j];
                    float xx1 = fmaxf(bi.x, bj.x), yy1 = fmaxf(bi.y, bj.y);
                    float xx2 = fminf(bi.z, bj.z), yy2 = fminf(bi.w, bj.w);
                    float inter = fmaxf(xx2 - xx1, 0.f) * fmaxf(yy2 - yy1, 0.f);
                    float iou = inter / (sarea[j] + ai - inter + 1e-9f);
                    if (iou > 0.6f) bb |= 1u << (j & 31);
                }
                adjW[i * 8 + w] = bb;
            }
        }
        __syncthreads();
        if (tid < 64) {   // wave-0 register-bitmask greedy resolve
            const int lane = tid;
            unsigned aw = (lane < 8) ? aliveW[lane] : 0u;
            int kn = kn0;
            while (kn < K_POST) {
                unsigned long long m = __ballot(aw != 0u);
                if (m == 0ull) break;
                int w0 = (int)(__ffsll(m) - 1);
                unsigned word = __shfl(aw, w0);
                int b = __ffs((int)word) - 1;
                int e = (w0 << 5) | b;
                unsigned rw = (lane < 8) ? adjW[e * 8 + lane] : 0u;
                aw &= ~rw;
                if (lane == w0) aw &= ~(1u << b);
                if (lane == 0) {
                    kbox[kn] = sbox[e]; kobox[kn] = obox[e];
                    karea[kn] = sarea[e]; kscor[kn] = sscor[e]; kcls[kn] = scls[e];
                }
                kn++;
            }
            if (lane == 0) { s_keptn = kn; s_done = (kn >= K_POST) ? 1 : 0; }
        }
        __syncthreads();
    }
    const int kn = s_keptn;
    if (tid < K_POST) {
        float4 b = make_float4(0.f, 0.f, 0.f, 0.f);
        float sc = 0.f, cl = 0.f, kp = 0.f;
        if (tid < kn) { b = kbox[tid]; sc = kscor[tid]; cl = (float)kcls[tid]; kp = 1.0f; }
        float* bo = out + (size_t)(img * K_POST + tid) * 4;
        bo[0] = b.x; bo[1] = b.y; bo[2] = b.z; bo[3] = b.w;
        out[N_IMG * K_POST * 4 + img * K_POST + tid] = sc;
        out[N_IMG * K_POST * 5 + img * K_POST + tid] = cl;
        out[N_IMG * K_POST * 6 + img * K_POST + tid] = kp;
    }
}

extern "C" void kernel_launch(void* const* d_in, const int* in_sizes, int n_in,
                              void* d_out, int out_size, void* d_ws, size_t ws_size,
                              hipStream_t stream) {
    const float* loc0 = (const float*)d_in[0];
    const float* cls0 = (const float*)d_in[1];
    const float* reg0 = (const float*)d_in[2];
    const float* ctr0 = (const float*)d_in[3];
    const float* loc1 = (const float*)d_in[4];
    const float* cls1 = (const float*)d_in[5];
    const float* reg1 = (const float*)d_in[6];
    const float* ctr1 = (const float*)d_in[7];
    const float* loc2 = (const float*)d_in[8];
    const float* cls2 = (const float*)d_in[9];
    const float* reg2 = (const float*)d_in[10];
    const float* ctr2 = (const float*)d_in[11];

    char* ws = (char*)d_ws;
    unsigned*           cnt   = (unsigned*)(ws + CNT_OFF);
    unsigned*           tbin  = (unsigned*)(ws + TBIN_OFF);
    unsigned*           h16   = (unsigned*)(ws + H16_OFF);
    unsigned*           h32   = (unsigned*)(ws + H32_OFF);
    unsigned long long* list  = (unsigned long long*)(ws + LIST_OFF);
    unsigned*           candF = (unsigned*)(ws + CANDF_OFF);
    float*              candS = (float*)(ws + CANDS_OFF);
    float4*             dbox  = (float4*)(ws + DBOX_OFF);
    int*                dcls  = (int*)(ws + DCLS_OFF);
    float*              out   = (float*)d_out;

    hipMemsetAsync(ws, 0, ZERO_BYTES, stream);

    hist_k<<<dim3(BPI, N_IMG), 256, 0, stream>>>(cls0, cls1, cls2, ctr0, ctr1, ctr2, h16);
    reduce_k<<<dim3(8, NPAIR), 256, 0, stream>>>(h16, h32);
    scan_k<<<NPAIR, 256, 0, stream>>>(h32, tbin);
    compact_k<<<dim3(BPI, N_IMG), 256, 0, stream>>>(cls0, cls1, cls2, ctr0, ctr1, ctr2, tbin, cnt, list);
    select_k<<<NPAIR, 1024, 0, stream>>>(cnt, list, candF, candS);
    decode_k<<<(NPAIR * K_PRE + 255) / 256, 256, 0, stream>>>(
        loc0, loc1, loc2, reg0, reg1, reg2, candF, candS, dbox, dcls);
    nms_k<<<N_IMG, 1024, 0, stream>>>(dbox, dcls, candS, out);
}

// Round 7
// 246.036 us; speedup vs baseline: 3.7869x; 1.1558x over previous
//
#include <hip/hip_runtime.h>
#include <math.h>

#define N_IMG 16
#define N_CLS 80
#define K_PRE 1000
#define K_POST 100
#define NPAIR 48
#define NBIN 4096
#define BSHIFT 20          // 12-bit bin = key >> 20
#define CAP 4096
#define IDXM 0xFFFFFu      // 20-bit packed (loc*80+c) index
#define CHUNK 256
#define CPB 20             // classes per block
#define BPI 56             // blocks per image: lvl0 10*4, lvl1 3*4, lvl2 1*4
#define NWRD (NBIN / 2)
#define SEG 1024           // sort segment size

// ---- workspace layout (bytes) ----
#define CNT_OFF    0                 // uint[48]                 -> 192
#define TBIN_OFF   192               // uint[48]                 -> 384
#define ZERO_BYTES 384
#define H16_OFF    384               // u32[896*2048]            -> 7340416
#define H32_OFF    7340416           // u32[48*4096]             -> 8126848
#define LIST_OFF   8126848           // u64[48*4096]             -> 9699712
#define CANDF_OFF  9699712           // uint[48000]              -> 9891712
#define CANDS_OFF  9891712           // float[48000]             -> 10083712
#define DBOX_OFF   10083712          // float4[48000] (16B-al)   -> 10851712
#define DCLS_OFF   10851712          // int[48000]               -> 11043712

__device__ __forceinline__ float sigm(float x) { return 1.0f / (1.0f + __expf(-x)); }
__device__ __forceinline__ int lvl_hw(int lvl) { return lvl == 0 ? 10000 : (lvl == 1 ? 2500 : 625); }

__device__ __forceinline__ void blk_map(int bx, int& lvl, int& locb, int& cg) {
    if (bx < 40)      { lvl = 0; locb = bx >> 2;        cg = bx & 3; }
    else if (bx < 52) { lvl = 1; locb = (bx - 40) >> 2; cg = bx & 3; }
    else              { lvl = 2; locb = 0;              cg = bx - 52; }
}

// ---------------- scan 1: private u16-slice histogram ----------------
__global__ __launch_bounds__(256) void hist_k(
        const float* __restrict__ cls0, const float* __restrict__ cls1, const float* __restrict__ cls2,
        const float* __restrict__ ctr0, const float* __restrict__ ctr1, const float* __restrict__ ctr2,
        unsigned* __restrict__ h16) {
    __shared__ unsigned lh[NBIN];
    const int img = blockIdx.y, bx = blockIdx.x;
    int lvl, locb, cg; blk_map(bx, lvl, locb, cg);
    const float* cls = lvl == 0 ? cls0 : (lvl == 1 ? cls1 : cls2);
    const float* ctr = lvl == 0 ? ctr0 : (lvl == 1 ? ctr1 : ctr2);
    const int HW = lvl_hw(lvl);
    for (int i = threadIdx.x; i < NBIN; i += 256) lh[i] = 0;
    __syncthreads();
    const int fi = locb * 256 + threadIdx.x;
    const int nf4 = HW >> 2;
    const float* clsI = cls + (size_t)img * N_CLS * HW + (size_t)cg * CPB * HW;
    const float* ctrI = ctr + (size_t)img * HW;
    if (fi < nf4) {
        const int base = fi * 4;
        float4 cv = *(const float4*)(ctrI + base);
        float s0 = sigm(cv.x), s1 = sigm(cv.y), s2 = sigm(cv.z), s3 = sigm(cv.w);
        #pragma unroll 5
        for (int c = 0; c < CPB; ++c) {
            float4 v = *(const float4*)(clsI + (size_t)c * HW + base);
            float cp;
            cp = sigm(v.x); if (cp > 0.05f) atomicAdd(&lh[__float_as_uint(cp * s0) >> BSHIFT], 1u);
            cp = sigm(v.y); if (cp > 0.05f) atomicAdd(&lh[__float_as_uint(cp * s1) >> BSHIFT], 1u);
            cp = sigm(v.z); if (cp > 0.05f) atomicAdd(&lh[__float_as_uint(cp * s2) >> BSHIFT], 1u);
            cp = sigm(v.w); if (cp > 0.05f) atomicAdd(&lh[__float_as_uint(cp * s3) >> BSHIFT], 1u);
        }
    } else if (fi == nf4) {
        for (int k = 0; k < (HW & 3); ++k) {
            int loc = nf4 * 4 + k;
            float cs = sigm(ctrI[loc]);
            for (int c = 0; c < CPB; ++c) {
                float cp = sigm(clsI[(size_t)c * HW + loc]);
                if (cp > 0.05f) atomicAdd(&lh[__float_as_uint(cp * cs) >> BSHIFT], 1u);
            }
        }
    }
    __syncthreads();
    unsigned* sp = h16 + (size_t)(img * BPI + bx) * NWRD;
    for (int w = threadIdx.x; w < NWRD; w += 256)
        sp[w] = (lh[2 * w] & 0xFFFFu) | (lh[2 * w + 1] << 16);
}

// ---------------- sum slices -> per-pair u32 histogram ----------------
__global__ __launch_bounds__(256) void reduce_k(const unsigned* __restrict__ h16,
                                                unsigned* __restrict__ h32) {
    const int p = blockIdx.y, chunk = blockIdx.x;
    const int img = p / 3, lvl = p % 3;
    const int sb = img * BPI + (lvl == 0 ? 0 : (lvl == 1 ? 40 : 52));
    const int ns = lvl == 0 ? 40 : (lvl == 1 ? 12 : 4);
    const int w = chunk * 256 + threadIdx.x;
    const unsigned* s0 = h16 + (size_t)sb * NWRD + w;
    unsigned lo = 0, hi = 0;
    for (int s = 0; s < ns; ++s) {
        unsigned u = s0[(size_t)s * NWRD];
        lo += u & 0xFFFFu; hi += u >> 16;
    }
    h32[(size_t)p * NBIN + 2 * w] = lo;
    h32[(size_t)p * NBIN + 2 * w + 1] = hi;
}

// ---------------- threshold bin per pair ----------------
__global__ __launch_bounds__(256) void scan_k(const unsigned* __restrict__ h32,
                                              unsigned* __restrict__ tbin) {
    __shared__ unsigned hs[NBIN];
    __shared__ unsigned csum[256];
    __shared__ unsigned suf[256];
    __shared__ unsigned res;
    const int p = blockIdx.x, t = threadIdx.x;
    for (int i = t; i < NBIN; i += 256) hs[i] = h32[(size_t)p * NBIN + i];
    if (t == 0) res = 0;
    __syncthreads();
    unsigned ms = 0;
    for (int j = 0; j < 16; ++j) ms += hs[t * 16 + j];
    csum[t] = ms;
    __syncthreads();
    if (t == 0) {
        unsigned a = 0;
        for (int i = 255; i >= 0; --i) { suf[i] = a; a += csum[i]; }
    }
    __syncthreads();
    unsigned A = suf[t];
    for (int j = 15; j >= 0; --j) {
        unsigned c = hs[t * 16 + j];
        if (A < K_PRE && A + c >= K_PRE) res = (unsigned)(t * 16 + j);
        A += c;
    }
    __syncthreads();
    if (t == 0) tbin[p] = res;
}

// ---------------- scan 2: LDS-staged compaction ----------------
__global__ __launch_bounds__(256) void compact_k(
        const float* __restrict__ cls0, const float* __restrict__ cls1, const float* __restrict__ cls2,
        const float* __restrict__ ctr0, const float* __restrict__ ctr1, const float* __restrict__ ctr2,
        const unsigned* __restrict__ tbin, unsigned* __restrict__ cnt, unsigned long long* __restrict__ list) {
    __shared__ unsigned long long buf[CAP];
    __shared__ unsigned lcnt, gbase;
    const int img = blockIdx.y, bx = blockIdx.x;
    int lvl, locb, cg; blk_map(bx, lvl, locb, cg);
    const float* cls = lvl == 0 ? cls0 : (lvl == 1 ? cls1 : cls2);
    const float* ctr = lvl == 0 ? ctr0 : (lvl == 1 ? ctr1 : ctr2);
    const int HW = lvl_hw(lvl);
    const int p = img * 3 + lvl;
    const unsigned Tb = tbin[p];
    if (threadIdx.x == 0) lcnt = 0;
    __syncthreads();
    const int fi = locb * 256 + threadIdx.x;
    const int nf4 = HW >> 2;
    const float* clsI = cls + (size_t)img * N_CLS * HW + (size_t)cg * CPB * HW;
    const float* ctrI = ctr + (size_t)img * HW;
    const int c0 = cg * CPB;
    if (fi < nf4) {
        const int base = fi * 4;
        float4 cv = *(const float4*)(ctrI + base);
        float css[4] = {sigm(cv.x), sigm(cv.y), sigm(cv.z), sigm(cv.w)};
        #pragma unroll 5
        for (int c = 0; c < CPB; ++c) {
            float4 v = *(const float4*)(clsI + (size_t)c * HW + base);
            float cps[4] = {sigm(v.x), sigm(v.y), sigm(v.z), sigm(v.w)};
            #pragma unroll
            for (int k = 0; k < 4; ++k) {
                if (cps[k] > 0.05f) {
                    unsigned key = __float_as_uint(cps[k] * css[k]);
                    if ((key >> BSHIFT) >= Tb) {
                        unsigned slot = atomicAdd(&lcnt, 1u);
                        unsigned idx = (unsigned)((base + k) * N_CLS + c0 + c);
                        if (slot < CAP)
                            buf[slot] = ((unsigned long long)key << 20) | (unsigned long long)(IDXM ^ idx);
                    }
                }
            }
        }
    } else if (fi == nf4) {
        for (int k = 0; k < (HW & 3); ++k) {
            int loc = nf4 * 4 + k;
            float cs = sigm(ctrI[loc]);
            for (int c = 0; c < CPB; ++c) {
                float cp = sigm(clsI[(size_t)c * HW + loc]);
                if (cp > 0.05f) {
                    unsigned key = __float_as_uint(cp * cs);
                    if ((key >> BSHIFT) >= Tb) {
                        unsigned slot = atomicAdd(&lcnt, 1u);
                        unsigned idx = (unsigned)(loc * N_CLS + c0 + c);
                        if (slot < CAP)
                            buf[slot] = ((unsigned long long)key << 20) | (unsigned long long)(IDXM ^ idx);
                    }
                }
            }
        }
    }
    __syncthreads();
    unsigned n = lcnt; if (n > CAP) n = CAP;
    if (threadIdx.x == 0 && n) gbase = atomicAdd(&cnt[p], n);
    __syncthreads();
    if (n) {
        unsigned gb = gbase;
        unsigned long long* lp = list + (size_t)p * CAP;
        for (unsigned i = threadIdx.x; i < n; i += 256) {
            unsigned g = gb + i;
            if (g < CAP) lp[g] = buf[i];
        }
    }
}

// ---------------- segment bitonic sort (1024 elems, shfl for j<=32) ----------------
__global__ __launch_bounds__(1024) void sort1_k(const unsigned* __restrict__ cnt,
                                                unsigned long long* __restrict__ list) {
    __shared__ unsigned long long sk[SEG];
    const int p = blockIdx.y, s = blockIdx.x, t = threadIdx.x;
    int n = (int)cnt[p]; if (n > CAP) n = CAP;
    unsigned long long* lp = list + (size_t)p * CAP + (size_t)(s << 10);
    int rem = n - (s << 10);
    unsigned long long v = (t < rem) ? lp[t] : 0ull;
    for (int k = 2; k <= SEG; k <<= 1) {
        for (int j = k >> 1; j >= 64; j >>= 1) {
            sk[t] = v;
            __syncthreads();
            unsigned long long o = sk[t ^ j];
            __syncthreads();
            bool takeMax = (((t & k) == 0) == ((t & j) == 0));
            v = takeMax ? (v > o ? v : o) : (v < o ? v : o);
        }
        int j0 = (k >> 1) < 64 ? (k >> 1) : 32;
        for (int j = j0; j >= 1; j >>= 1) {
            unsigned long long o = __shfl_xor(v, j);
            bool takeMax = (((t & k) == 0) == ((t & j) == 0));
            v = takeMax ? (v > o ? v : o) : (v < o ? v : o);
        }
    }
    lp[t] = v;   // sorted descending; zeros (padding) at the tail
}

// ---------------- merge-path: global rank across 4 sorted segments ----------------
__global__ __launch_bounds__(1024) void merge_k(const unsigned long long* __restrict__ list,
                                                unsigned* __restrict__ candF, float* __restrict__ candS) {
    __shared__ unsigned long long sk[CAP];   // 32 KB
    const int p = blockIdx.x, t = threadIdx.x;
    const unsigned long long* lp = list + (size_t)p * CAP;
    for (int i = t; i < CAP; i += 1024) sk[i] = lp[i];
    if (t < K_PRE) { candS[p * K_PRE + t] = -1.0f; candF[p * K_PRE + t] = 0u; }
    __syncthreads();
    if (t < K_PRE) {
        #pragma unroll
        for (int q = 0; q < 4; ++q) {
            unsigned long long v = sk[(q << 10) | t];
            if (v == 0ull) continue;            // padding / empty
            int rank = t;                       // strictly-greater count in own segment == pos (keys unique)
            #pragma unroll
            for (int s2 = 0; s2 < 4; ++s2) {
                if (s2 == q) continue;
                const unsigned long long* seg = sk + (s2 << 10);
                int lo = 0, hi = SEG;
                while (lo < hi) {
                    int m = (lo + hi) >> 1;
                    if (seg[m] > v) lo = m + 1; else hi = m;
                }
                rank += lo;
            }
            if (rank < K_PRE) {
                int o = p * K_PRE + rank;
                candS[o] = __uint_as_float((unsigned)(v >> 20));
                candF[o] = IDXM ^ (unsigned)(v & IDXM);
            }
        }
    }
}

// ---------------- parallel box decode ----------------
__global__ __launch_bounds__(256) void decode_k(
        const float* __restrict__ loc0, const float* __restrict__ loc1, const float* __restrict__ loc2,
        const float* __restrict__ reg0, const float* __restrict__ reg1, const float* __restrict__ reg2,
        const unsigned* __restrict__ candF, const float* __restrict__ candS,
        float4* __restrict__ dbox, int* __restrict__ dcls) {
    int i = blockIdx.x * blockDim.x + threadIdx.x;
    if (i >= NPAIR * K_PRE) return;
    int p = i / K_PRE, slot = i % K_PRE;
    int img = p / 3, lvl = p % 3;
    int o = img * 3000 + lvl * K_PRE + slot;
    float s = candS[i];
    if (!(s > 0.0f)) { dbox[o] = make_float4(0.f, 0.f, 0.f, 0.f); dcls[o] = 0; return; }
    const float* locs = lvl == 0 ? loc0 : (lvl == 1 ? loc1 : loc2);
    const float* rg = lvl == 0 ? reg0 : (lvl == 1 ? reg1 : reg2);
    const int HW = lvl_hw(lvl);
    const float st = lvl == 0 ? 8.f : (lvl == 1 ? 16.f : 32.f);
    unsigned fi = candF[i];
    int loc = (int)(fi / (unsigned)N_CLS);
    int c = (int)(fi % (unsigned)N_CLS) + 1;
    const float* rb = rg + (size_t)img * 4 * HW;
    float lv = rb[loc] * st, tv = rb[HW + loc] * st;
    float rv = rb[2 * HW + loc] * st, bv = rb[3 * HW + loc] * st;
    float x = locs[2 * loc], y = locs[2 * loc + 1];
    float x1 = fminf(fmaxf(x - lv, 0.f), 800.f);
    float y1 = fminf(fmaxf(y - tv, 0.f), 800.f);
    float x2 = fminf(fmaxf(x + rv, 0.f), 800.f);
    float y2 = fminf(fmaxf(y + bv, 0.f), 800.f);
    dbox[o] = make_float4(x1, y1, x2, y2);
    dcls[o] = c;
}

// ---------------- merge 3 sorted lists + bitmask greedy NMS (1024 thr) ----------------
__global__ __launch_bounds__(1024) void nms_k(
        const float4* __restrict__ dbox, const int* __restrict__ dcls,
        const float* __restrict__ candS, float* __restrict__ out) {
    __shared__ float skey[3000];
    __shared__ unsigned short sidx[3000];
    __shared__ float4 sbox[CHUNK], obox[CHUNK];
    __shared__ float sarea[CHUNK], sscor[CHUNK];
    __shared__ int scls[CHUNK];
    __shared__ unsigned adjW[CHUNK * 8];
    __shared__ unsigned aliveW[8];
    __shared__ float4 kbox[K_POST], kobox[K_POST];
    __shared__ float karea[K_POST], kscor[K_POST];
    __shared__ int kcls[K_POST];
    __shared__ int s_keptn, s_done;
    const int img = blockIdx.x, tid = threadIdx.x;
    if (tid == 0) { s_keptn = 0; s_done = 0; }
    for (int i = tid; i < 3000; i += 1024) skey[i] = candS[img * 3000 + i];
    __syncthreads();
    for (int e = tid; e < 3000; e += 1024) {
        int l = e >= 2000 ? 2 : (e >= 1000 ? 1 : 0);
        int slot = e - l * 1000;
        float s = skey[e];
        int rank = slot;
        for (int l2 = 0; l2 < 3; ++l2) {
            if (l2 == l) continue;
            const float* kb = skey + l2 * 1000;
            const bool eq = l2 < l;
            int lo = 0, hi = 1000;
            while (lo < hi) {
                int m = (lo + hi) >> 1;
                float v = kb[m];
                bool go = eq ? (v >= s) : (v > s);
                lo = go ? m + 1 : lo;
                hi = go ? hi : m;
            }
            rank += lo;
        }
        sidx[rank] = (unsigned short)e;
    }
    __syncthreads();
    for (int base = 0; base < 3000; base += CHUNK) {
        if (s_done) break;
        const int kn0 = s_keptn;
        if (tid < 8) aliveW[tid] = 0u;
        __syncthreads();
        if (tid < CHUNK) {
            const int q = tid;
            const int r = base + q;
            float4 bx = make_float4(0.f, 0.f, 0.f, 0.f), ox = bx;
            float ar = 0.f, ssc = 0.f; int cl = 0, alive = 0;
            if (r < 3000) {
                int e = sidx[r];
                float s = skey[e];
                if (s > 0.f) {
                    bx = dbox[img * 3000 + e];
                    cl = dcls[img * 3000 + e];
                    float off = (float)cl * 4096.0f;
                    ox = make_float4(bx.x + off, bx.y + off, bx.z + off, bx.w + off);
                    ar = (ox.z - ox.x) * (ox.w - ox.y);
                    ssc = sqrtf(s);
                    alive = 1;
                    for (int k = 0; k < kn0; ++k) {
                        float4 kb = kobox[k];
                        float xx1 = fmaxf(kb.x, ox.x), yy1 = fmaxf(kb.y, ox.y);
                        float xx2 = fminf(kb.z, ox.z), yy2 = fminf(kb.w, ox.w);
                        float inter = fmaxf(xx2 - xx1, 0.f) * fmaxf(yy2 - yy1, 0.f);
                        float iou = inter / (ar + karea[k] - inter + 1e-9f);
                        if (iou > 0.6f) { alive = 0; break; }
                    }
                }
            }
            sbox[q] = bx; obox[q] = ox; sarea[q] = ar; sscor[q] = ssc; scls[q] = cl;
            if (alive) atomicOr(&aliveW[q >> 5], 1u << (q & 31));
        }
        __syncthreads();
        {
            const int g = tid >> 8;
            const int i = tid & 255;
            float4 bi = obox[i];
            float ai = sarea[i];
            #pragma unroll
            for (int ww = 0; ww < 2; ++ww) {
                const int w = g * 2 + ww;
                unsigned bb = 0;
                int j0 = w << 5;
                int js = j0 > i + 1 ? j0 : i + 1;
                for (int j = js; j < j0 + 32; ++j) {
                    float4 bj = obox[j];
                    float xx1 = fmaxf(bi.x, bj.x), yy1 = fmaxf(bi.y, bj.y);
                    float xx2 = fminf(bi.z, bj.z), yy2 = fminf(bi.w, bj.w);
                    float inter = fmaxf(xx2 - xx1, 0.f) * fmaxf(yy2 - yy1, 0.f);
                    float iou = inter / (sarea[j] + ai - inter + 1e-9f);
                    if (iou > 0.6f) bb |= 1u << (j & 31);
                }
                adjW[i * 8 + w] = bb;
            }
        }
        __syncthreads();
        if (tid < 64) {
            const int lane = tid;
            unsigned aw = (lane < 8) ? aliveW[lane] : 0u;
            int kn = kn0;
            while (kn < K_POST) {
                unsigned long long m = __ballot(aw != 0u);
                if (m == 0ull) break;
                int w0 = (int)(__ffsll(m) - 1);
                unsigned word = __shfl(aw, w0);
                int b = __ffs((int)word) - 1;
                int e = (w0 << 5) | b;
                unsigned rw = (lane < 8) ? adjW[e * 8 + lane] : 0u;
                aw &= ~rw;
                if (lane == w0) aw &= ~(1u << b);
                if (lane == 0) {
                    kbox[kn] = sbox[e]; kobox[kn] = obox[e];
                    karea[kn] = sarea[e]; kscor[kn] = sscor[e]; kcls[kn] = scls[e];
                }
                kn++;
            }
            if (lane == 0) { s_keptn = kn; s_done = (kn >= K_POST) ? 1 : 0; }
        }
        __syncthreads();
    }
    const int kn = s_keptn;
    if (tid < K_POST) {
        float4 b = make_float4(0.f, 0.f, 0.f, 0.f);
        float sc = 0.f, cl = 0.f, kp = 0.f;
        if (tid < kn) { b = kbox[tid]; sc = kscor[tid]; cl = (float)kcls[tid]; kp = 1.0f; }
        float* bo = out + (size_t)(img * K_POST + tid) * 4;
        bo[0] = b.x; bo[1] = b.y; bo[2] = b.z; bo[3] = b.w;
        out[N_IMG * K_POST * 4 + img * K_POST + tid] = sc;
        out[N_IMG * K_POST * 5 + img * K_POST + tid] = cl;
        out[N_IMG * K_POST * 6 + img * K_POST + tid] = kp;
    }
}

extern "C" void kernel_launch(void* const* d_in, const int* in_sizes, int n_in,
                              void* d_out, int out_size, void* d_ws, size_t ws_size,
                              hipStream_t stream) {
    const float* loc0 = (const float*)d_in[0];
    const float* cls0 = (const float*)d_in[1];
    const float* reg0 = (const float*)d_in[2];
    const float* ctr0 = (const float*)d_in[3];
    const float* loc1 = (const float*)d_in[4];
    const float* cls1 = (const float*)d_in[5];
    const float* reg1 = (const float*)d_in[6];
    const float* ctr1 = (const float*)d_in[7];
    const float* loc2 = (const float*)d_in[8];
    const float* cls2 = (const float*)d_in[9];
    const float* reg2 = (const float*)d_in[10];
    const float* ctr2 = (const float*)d_in[11];

    char* ws = (char*)d_ws;
    unsigned*           cnt   = (unsigned*)(ws + CNT_OFF);
    unsigned*           tbin  = (unsigned*)(ws + TBIN_OFF);
    unsigned*           h16   = (unsigned*)(ws + H16_OFF);
    unsigned*           h32   = (unsigned*)(ws + H32_OFF);
    unsigned long long* list  = (unsigned long long*)(ws + LIST_OFF);
    unsigned*           candF = (unsigned*)(ws + CANDF_OFF);
    float*              candS = (float*)(ws + CANDS_OFF);
    float4*             dbox  = (float4*)(ws + DBOX_OFF);
    int*                dcls  = (int*)(ws + DCLS_OFF);
    float*              out   = (float*)d_out;

    hipMemsetAsync(ws, 0, ZERO_BYTES, stream);

    hist_k<<<dim3(BPI, N_IMG), 256, 0, stream>>>(cls0, cls1, cls2, ctr0, ctr1, ctr2, h16);
    reduce_k<<<dim3(8, NPAIR), 256, 0, stream>>>(h16, h32);
    scan_k<<<NPAIR, 256, 0, stream>>>(h32, tbin);
    compact_k<<<dim3(BPI, N_IMG), 256, 0, stream>>>(cls0, cls1, cls2, ctr0, ctr1, ctr2, tbin, cnt, list);
    sort1_k<<<dim3(4, NPAIR), 1024, 0, stream>>>(cnt, list);
    merge_k<<<NPAIR, 1024, 0, stream>>>(list, candF, candS);
    decode_k<<<(NPAIR * K_PRE + 255) / 256, 256, 0, stream>>>(
        loc0, loc1, loc2, reg0, reg1, reg2, candF, candS, dbox, dcls);
    nms_k<<<N_IMG, 1024, 0, stream>>>(dbox, dcls, candS, out);
}